// Round 4
// baseline (360.877 us; speedup 1.0000x reference)
//
#include <hip/hip_runtime.h>
#include <stdint.h>
#include <stddef.h>

// ---------- types ----------
typedef short s8v __attribute__((ext_vector_type(8)));   // 8 bf16 (4 VGPRs) MFMA A/B frag
typedef short s4v __attribute__((ext_vector_type(4)));   // 4 bf16
typedef float f4v __attribute__((ext_vector_type(4)));   // MFMA C/D frag

#define DEV static __device__ __forceinline__

// Problem constants: B=32 T=512 VOCAB=1024 D=256 H=256 O=1024 L=2
// Collapsed pipeline (4 dispatches):
//   wgemm : a0 = W0@Wemb, a1 = W1@V0, a2 = Wout@V1   (straight from f32 inputs)
//   gemm_x: Xc0 = x(f32) @ a0^T -> scan layout
//   scan2 : both RNN layers in ONE chain (layer-1 lagged 1 step; xc1 never global)
//   gemm_logsm: softmax_T(h1 @ a2^T) fused

DEV short f2b(float f) {
  union { float f; uint32_t u; } v; v.f = f;
  uint32_t u = v.u;
  uint32_t r = (u + 0x7fffu + ((u >> 16) & 1u)) >> 16;   // RNE
  return (short)(uint16_t)r;
}
DEV float b2f(short h) {
  union { uint32_t u; float f; } v; v.u = ((uint32_t)(uint16_t)h) << 16;
  return v.f;
}

DEV void gl_lds16(const void* g, void* l) {
  __builtin_amdgcn_global_load_lds(
      (__attribute__((address_space(1))) void*)(uintptr_t)(g),
      (__attribute__((address_space(3))) void*)(l), 16, 0, 0);
}

// scan layout row remap: m = b*512 + t  ->  ((g*512 + t)*16 + s), g=b>>4, s=b&15
DEV int rmap_scan(int m) {
  int b = m >> 9;
  int t = m & 511;
  return ((((b >> 4) << 9) | t) << 4) | (b & 15);
}

// ---------- weight-product GEMMs straight from f32 (replaces prep + gemm_w3) ----
// C[m,n] = sum_k A[m,k] * Bsrc[k,n]  (Bsrc consumed transposed at frag-build time).
// A: f32 rows staged+converted to bf16 (pitch 72 -> 2-way banks). B: f32 staged
// LINEAR via global_load_lds (no convert), frag-build does 8x ds_read_b32 + cvt
// at stride 512B -> lanes spread over consecutive dwords (conflict-free).
DEV void wgemm_body(const float* __restrict__ Af, const float* __restrict__ Bsrc,
                    short* __restrict__ C, int lda, int ldbs, int ldc,
                    int m0, int n0, int tid, short* As, float* Bf) {
  const int w = tid >> 6, lane = tid & 63, quad = lane >> 4, sid = lane & 15;
  const int wm = (w >> 1) * 64, wn = (w & 1) * 64;

  f4v acc[4][4];
#pragma unroll
  for (int i = 0; i < 4; ++i)
#pragma unroll
    for (int j = 0; j < 4; ++j) acc[i][j] = (f4v){0.f, 0.f, 0.f, 0.f};

  for (int k0 = 0; k0 < 256; k0 += 64) {
    // B: 64 k-rows x 128 n f32, linear direct-to-LDS (2048 16B chunks)
#pragma unroll
    for (int q = 0; q < 8; ++q) {
      int lin = q * 256 + tid;
      int kr = lin >> 5, nc = (lin & 31) << 2;
      gl_lds16(Bsrc + (size_t)(k0 + kr) * ldbs + n0 + nc, &Bf[lin << 2]);
    }
    // A: 128 rows x 64 k f32 -> bf16, pitch 72
#pragma unroll
    for (int q = 0; q < 4; ++q) {
      int lin = q * 256 + tid;
      int row = lin >> 3, kc = (lin & 7) << 3;
      const float* ap = Af + (size_t)(m0 + row) * lda + k0 + kc;
      float4 v0 = *(const float4*)ap;
      float4 v1 = *(const float4*)(ap + 4);
      s8v p;
      p[0] = f2b(v0.x); p[1] = f2b(v0.y); p[2] = f2b(v0.z); p[3] = f2b(v0.w);
      p[4] = f2b(v1.x); p[5] = f2b(v1.y); p[6] = f2b(v1.z); p[7] = f2b(v1.w);
      *(s8v*)&As[row * 72 + kc] = p;
    }
    __syncthreads();
#pragma unroll
    for (int kb = 0; kb < 2; ++kb) {
      s8v af[4], bf[4];
#pragma unroll
      for (int mt = 0; mt < 4; ++mt)
        af[mt] = *(const s8v*)&As[(wm + 16 * mt + sid) * 72 + kb * 32 + quad * 8];
#pragma unroll
      for (int nt = 0; nt < 4; ++nt) {
        s8v b;
#pragma unroll
        for (int j = 0; j < 8; ++j)
          b[j] = f2b(Bf[(kb * 32 + quad * 8 + j) * 128 + wn + 16 * nt + sid]);
        bf[nt] = b;
      }
#pragma unroll
      for (int mt = 0; mt < 4; ++mt)
#pragma unroll
        for (int nt = 0; nt < 4; ++nt)
          acc[mt][nt] = __builtin_amdgcn_mfma_f32_16x16x32_bf16(af[mt], bf[nt], acc[mt][nt], 0, 0, 0);
    }
    __syncthreads();
  }
#pragma unroll
  for (int mt = 0; mt < 4; ++mt)
#pragma unroll
    for (int r = 0; r < 4; ++r) {
      int gm = m0 + wm + 16 * mt + 4 * quad + r;
      size_t ro = (size_t)gm * ldc;
#pragma unroll
      for (int nt = 0; nt < 4; ++nt)
        C[ro + n0 + wn + 16 * nt + sid] = f2b(acc[mt][nt][r]);
    }
}

__global__ __launch_bounds__(256) void wgemm(const float* __restrict__ wemb,
                                             const float* __restrict__ wf,
                                             const float* __restrict__ vfp,
                                             const float* __restrict__ wout,
                                             short* __restrict__ a0,
                                             short* __restrict__ a1,
                                             short* __restrict__ a2) {
  __shared__ __align__(16) short As[128 * 72];   // 18 KB
  __shared__ __align__(16) float Bf[64 * 128];   // 32 KB
  const int blk = blockIdx.x, tid = threadIdx.x;
  if (blk < 16) {          // a0 = W0 @ Wemb : [256,1024], 2x8 tiles
    wgemm_body(wf, wemb, a0, 256, 1024, 1024,
               (blk >> 3) * 128, (blk & 7) * 128, tid, As, Bf);
  } else if (blk < 20) {   // a1 = W1 @ V0 : [256,256], 2x2 tiles
    int b = blk - 16;
    wgemm_body(wf + 65536, vfp, a1, 256, 256, 256,
               (b >> 1) * 128, (b & 1) * 128, tid, As, Bf);
  } else {                 // a2 = Wout @ V1 : [1024,256], 8x2 tiles
    int b = blk - 20;
    wgemm_body(wout, vfp + 65536, a2, 256, 256, 256,
               (b >> 1) * 128, (b & 1) * 128, tid, As, Bf);
  }
}

// ---------- Xc0 = x(f32) @ A0^T, LDS-staged, BM=32 x BN=256, 2 blocks/CU ----------
__global__ __launch_bounds__(256, 2) void gemm_x(const float* __restrict__ Xf,
                                                 const short* __restrict__ Bw,
                                                 short* __restrict__ C) {
  __shared__ __align__(16) short As[32 * 72];    // 4.5 KB (pitch 72 -> 2-way banks)
  __shared__ __align__(16) short Bs[256 * 64];   // 32 KB
  const int tid = threadIdx.x;
  const int w = tid >> 6, lane = tid & 63, quad = lane >> 4, sid = lane & 15;
  const int m0 = blockIdx.x * 32;
  const int wn = w * 64;

  f4v acc[2][4];
#pragma unroll
  for (int i = 0; i < 2; ++i)
#pragma unroll
    for (int j = 0; j < 4; ++j) acc[i][j] = (f4v){0.f, 0.f, 0.f, 0.f};

  for (int k0 = 0; k0 < 1024; k0 += 64) {
    // B: 256 rows x 64 k = 2048 16B chunks, direct-to-LDS
#pragma unroll
    for (int q = 0; q < 8; ++q) {
      int lin = q * 256 + tid;
      gl_lds16(Bw + (size_t)(lin >> 3) * 1024 + k0 + ((lin & 7) << 3), &Bs[lin << 3]);
    }
    // A: 32 rows x 64 k f32 -> one 16B bf16 chunk per thread
    {
      int row = tid >> 3, kc = (tid & 7) << 3;
      const float* ap = &Xf[(size_t)(m0 + row) * 1024 + k0 + kc];
      float4 v0 = *(const float4*)ap;
      float4 v1 = *(const float4*)(ap + 4);
      s8v p;
      p[0] = f2b(v0.x); p[1] = f2b(v0.y); p[2] = f2b(v0.z); p[3] = f2b(v0.w);
      p[4] = f2b(v1.x); p[5] = f2b(v1.y); p[6] = f2b(v1.z); p[7] = f2b(v1.w);
      *(s8v*)&As[row * 72 + kc] = p;
    }
    __syncthreads();
#pragma unroll
    for (int kb = 0; kb < 2; ++kb) {
      s8v af[2], bf[4];
#pragma unroll
      for (int mt = 0; mt < 2; ++mt)
        af[mt] = *(const s8v*)&As[(16 * mt + sid) * 72 + kb * 32 + quad * 8];
#pragma unroll
      for (int nt = 0; nt < 4; ++nt)
        bf[nt] = *(const s8v*)&Bs[(wn + 16 * nt + sid) * 64 + kb * 32 + quad * 8];
#pragma unroll
      for (int mt = 0; mt < 2; ++mt)
#pragma unroll
        for (int nt = 0; nt < 4; ++nt)
          acc[mt][nt] = __builtin_amdgcn_mfma_f32_16x16x32_bf16(af[mt], bf[nt], acc[mt][nt], 0, 0, 0);
    }
    __syncthreads();
  }

#pragma unroll
  for (int mt = 0; mt < 2; ++mt)
#pragma unroll
    for (int r = 0; r < 4; ++r) {
      int gm = m0 + 16 * mt + 4 * quad + r;
      size_t ro = (size_t)rmap_scan(gm) * 256;
#pragma unroll
      for (int nt = 0; nt < 4; ++nt)
        C[ro + wn + 16 * nt + sid] = f2b(acc[mt][nt][r]);
    }
}

// ---------- both RNN layers in one chained scan ----------
// Step invariant (top of step t): h0T[pr] = h0_{t-1}, h1T[pr] = h1_{t-2}.
// Step t computes: xc1_{t-1} = A1 h0_{t-1};  h1_{t-1} = U1 h1_{t-2} + xc1_{t-1};
//                  h0_t = U0 h0_{t-1} + xc0_t.   One barrier per step.
// xc1 never touches global. U0/U1 converted from f32 at init (prep eliminated).
// hT pitch 264 shorts = 132 dw === 4 (mod 32): frag reads are 2-way banked = free
// (old pitch 288 = 144 dw === 16 -> 8-way conflict on the serial critical path).
// CL=4, WU=12 per layer: steps = CL + 2*WU + 1 = 29; grid 128 chunks x 2 g = 256.
__global__ __launch_bounds__(256, 1) void scan2(const float* __restrict__ Uf,
                                                const short* __restrict__ A1b,
                                                const short* __restrict__ Xc0,
                                                short* __restrict__ hbuf,
                                                const float* __restrict__ hinit) {
  constexpr int CL = 4, WU = 12, PITCH = 264;
  __shared__ __align__(16) short h0T[2][16 * PITCH];
  __shared__ __align__(16) short h1T[2][16 * PITCH];
  const int tid = threadIdx.x;
  const int w = tid >> 6, lane = tid & 63, quad = lane >> 4, sid = lane & 15;
  const int c = blockIdx.x & 127;
  const int g = blockIdx.x >> 7;

  s8v uf0[4][8], vf[4][8], uf1[4][8];
#pragma unroll
  for (int mt = 0; mt < 4; ++mt)
#pragma unroll
    for (int kb = 0; kb < 8; ++kb) {
      int i = 64 * w + 16 * mt + sid;
      int k = 32 * kb + quad * 8;
      const float* u0 = Uf + (size_t)i * 256 + k;
      const float* u1 = Uf + 65536 + (size_t)i * 256 + k;
      float4 a = *(const float4*)u0, b = *(const float4*)(u0 + 4);
      s8v p;
      p[0] = f2b(a.x); p[1] = f2b(a.y); p[2] = f2b(a.z); p[3] = f2b(a.w);
      p[4] = f2b(b.x); p[5] = f2b(b.y); p[6] = f2b(b.z); p[7] = f2b(b.w);
      uf0[mt][kb] = p;
      a = *(const float4*)u1; b = *(const float4*)(u1 + 4);
      p[0] = f2b(a.x); p[1] = f2b(a.y); p[2] = f2b(a.z); p[3] = f2b(a.w);
      p[4] = f2b(b.x); p[5] = f2b(b.y); p[6] = f2b(b.z); p[7] = f2b(b.w);
      uf1[mt][kb] = p;
      vf[mt][kb] = *(const s8v*)&A1b[i * 256 + k];
    }

  const int s1 = (c * CL <= WU) ? 0 : c * CL - WU;   // first layer-1 time index
  const int t0 = (s1 <= WU) ? 0 : s1 - WU;           // first layer-0 time index
  const int t1 = (c + 1) * CL;                       // loop runs t0..t1 inclusive

  for (int idx = tid; idx < 4096; idx += 256) {
    int s = idx >> 8, i = idx & 255;
    short h0s = (t0 == 0) ? f2b(hinit[i]) : (short)0;
    short h1s = (s1 == 0) ? f2b(hinit[256 + i]) : (short)0;
    h0T[0][s * PITCH + i] = h0s; h0T[1][s * PITCH + i] = h0s;
    h1T[0][s * PITCH + i] = h1s; h1T[1][s * PITCH + i] = h1s;
  }
  __syncthreads();

  int pr = 0;
  for (int t = t0; t <= t1; ++t) {
    const bool doh0 = (t < t1);
    const bool dol1 = (t > s1);
    s4v xc0[4];
    if (doh0) {
      const int xb = (((g << 9) + t) * 16 + sid) * 256;
#pragma unroll
      for (int mt = 0; mt < 4; ++mt)
        xc0[mt] = *(const s4v*)&Xc0[xb + 64 * w + 16 * mt + 4 * quad];
    }

    f4v acc1[4], acc0[4];
#pragma unroll
    for (int mt = 0; mt < 4; ++mt) {
      acc1[mt] = (f4v){0.f, 0.f, 0.f, 0.f};
      acc0[mt] = (f4v){0.f, 0.f, 0.f, 0.f};
    }
#pragma unroll
    for (int kb = 0; kb < 8; ++kb) {
      s8v b0 = *(const s8v*)&h0T[pr][sid * PITCH + kb * 32 + quad * 8];
      if (dol1) {
        s8v b1 = *(const s8v*)&h1T[pr][sid * PITCH + kb * 32 + quad * 8];
#pragma unroll
        for (int mt = 0; mt < 4; ++mt) {
          acc1[mt] = __builtin_amdgcn_mfma_f32_16x16x32_bf16(vf[mt][kb], b0, acc1[mt], 0, 0, 0);
          acc1[mt] = __builtin_amdgcn_mfma_f32_16x16x32_bf16(uf1[mt][kb], b1, acc1[mt], 0, 0, 0);
        }
      }
      if (doh0)
#pragma unroll
        for (int mt = 0; mt < 4; ++mt)
          acc0[mt] = __builtin_amdgcn_mfma_f32_16x16x32_bf16(uf0[mt][kb], b0, acc0[mt], 0, 0, 0);
    }

    if (dol1) {   // h1_{t-1} done: store + emit
      const int ob = (((g << 9) + (t - 1)) * 16 + sid) * 256;
      const bool emit = (t - 1 >= c * CL);
#pragma unroll
      for (int mt = 0; mt < 4; ++mt) {
        int ioff = 64 * w + 16 * mt + 4 * quad;
        s4v p; p.x = f2b(acc1[mt].x); p.y = f2b(acc1[mt].y);
        p.z = f2b(acc1[mt].z); p.w = f2b(acc1[mt].w);
        *(s4v*)&h1T[pr ^ 1][sid * PITCH + ioff] = p;
        if (emit) *(s4v*)&hbuf[ob + ioff] = p;
      }
    }
    if (doh0) {   // h0_t
#pragma unroll
      for (int mt = 0; mt < 4; ++mt) {
        int ioff = 64 * w + 16 * mt + 4 * quad;
        f4v v = acc0[mt];
        v.x += b2f(xc0[mt].x); v.y += b2f(xc0[mt].y);
        v.z += b2f(xc0[mt].z); v.w += b2f(xc0[mt].w);
        s4v p; p.x = f2b(v.x); p.y = f2b(v.y); p.z = f2b(v.z); p.w = f2b(v.w);
        *(s4v*)&h0T[pr ^ 1][sid * PITCH + ioff] = p;
      }
    }
    pr ^= 1;
    __syncthreads();
  }
}

// ---------- fused logits GEMM + softmax over T ----------
// LDS-staged (pitch-40 As: bank-conflict-free). XCD-friendly block mapping:
// b = blk&31 -> the 16 ot-blocks sharing a b-panel land on the same XCD's L2.
__global__ __launch_bounds__(256, 2) void gemm_logsm(const short* __restrict__ A,
                                                     const short* __restrict__ Bw,
                                                     float* __restrict__ out) {
  __shared__ __align__(16) short As[512 * 40];   // [t][k-local 32, pitch 40]
  __shared__ __align__(16) short Bs[64 * 32];    // [kch 0..3][row 0..63] of 8 shorts
  __shared__ float2 red[4][64];                  // per-wave (max,sum) per col
  const int tid = threadIdx.x;
  const int w = tid >> 6, lane = tid & 63, quad = lane >> 4, sid = lane & 15;
  const int b = blockIdx.x & 31, ot = blockIdx.x >> 5;
  const int g = b >> 4, si = b & 15;

  f4v acc[8][4];
#pragma unroll
  for (int i = 0; i < 8; ++i)
#pragma unroll
    for (int j = 0; j < 4; ++j) acc[i][j] = (f4v){0.f, 0.f, 0.f, 0.f};

  for (int k0 = 0; k0 < 256; k0 += 32) {
    // A: 2048 8-short chunks; kchunk in the LOW bits -> 4 lanes read 64 B contiguous
#pragma unroll
    for (int q = 0; q < 8; ++q) {
      int lin = q * 256 + tid;
      int t = lin >> 2, kch = lin & 3;
      size_t ar = ((size_t)(g * 512 + t) * 16 + si) * 256;
      s8v v = *(const s8v*)(A + ar + k0 + kch * 8);
      *(s8v*)&As[t * 40 + kch * 8] = v;
    }
    // B: 256 chunks, [kch][row] layout
    {
      int row = tid & 63, kch = tid >> 6;
      s8v v = *(const s8v*)(Bw + (size_t)(ot * 64 + row) * 256 + k0 + kch * 8);
      *(s8v*)&Bs[tid << 3] = v;
    }
    __syncthreads();
    s8v bf[4];
#pragma unroll
    for (int nt = 0; nt < 4; ++nt)
      bf[nt] = *(const s8v*)&Bs[(quad * 64 + 16 * nt + sid) * 8];
#pragma unroll
    for (int mt = 0; mt < 8; ++mt) {
      s8v af = *(const s8v*)&As[(128 * w + 16 * mt + sid) * 40 + quad * 8];
#pragma unroll
      for (int nt = 0; nt < 4; ++nt)
        acc[mt][nt] = __builtin_amdgcn_mfma_f32_16x16x32_bf16(af, bf[nt], acc[mt][nt], 0, 0, 0);
    }
    __syncthreads();
  }

  // softmax over t: lane holds cols {16nt+sid}, rows {128w + 16mt + 4quad + r}
#pragma unroll
  for (int nt = 0; nt < 4; ++nt) {
    float m = -3.0e38f;
#pragma unroll
    for (int mt = 0; mt < 8; ++mt)
#pragma unroll
      for (int r = 0; r < 4; ++r) m = fmaxf(m, acc[mt][nt][r]);
    float sum = 0.f;
#pragma unroll
    for (int mt = 0; mt < 8; ++mt)
#pragma unroll
      for (int r = 0; r < 4; ++r) sum += __expf(acc[mt][nt][r] - m);
#pragma unroll
    for (int d = 16; d < 64; d <<= 1) {
      float om = __shfl_xor(m, d, 64);
      float os = __shfl_xor(sum, d, 64);
      float nm = fmaxf(m, om);
      sum = sum * __expf(m - nm) + os * __expf(om - nm);
      m = nm;
    }
    if (quad == 0) red[w][16 * nt + sid] = (float2){m, sum};
  }
  __syncthreads();
#pragma unroll
  for (int nt = 0; nt < 4; ++nt) {
    float M = -3.0e38f, S = 0.f;
#pragma unroll
    for (int ww = 0; ww < 4; ++ww) {
      float2 r2 = red[ww][16 * nt + sid];
      float nm = fmaxf(M, r2.x);
      S = S * __expf(M - nm) + r2.y * __expf(r2.x - nm);
      M = nm;
    }
    const float inv = 1.0f / S;
    const size_t cbase = (size_t)b * 512 * 1024 + ot * 64 + 16 * nt + sid;
#pragma unroll
    for (int mt = 0; mt < 8; ++mt)
#pragma unroll
      for (int r = 0; r < 4; ++r) {
        int t = 128 * w + 16 * mt + 4 * quad + r;
        out[cbase + (size_t)t * 1024] = __expf(acc[mt][nt][r] - M) * inv;
      }
  }
}

// ---------- host ----------
extern "C" void kernel_launch(void* const* d_in, const int* in_sizes, int n_in,
                              void* d_out, int out_size, void* d_ws, size_t ws_size,
                              hipStream_t stream) {
  (void)in_sizes; (void)n_in; (void)out_size; (void)ws_size;
  const float* xf   = (const float*)d_in[0];
  const float* hs   = (const float*)d_in[1];
  const float* wemb = (const float*)d_in[2];
  const float* wf   = (const float*)d_in[3];
  const float* ufp  = (const float*)d_in[4];
  const float* vfp  = (const float*)d_in[5];
  const float* wout = (const float*)d_in[6];

  char* ws = (char*)d_ws;
  short* hbuf = (short*)(ws);              // 8,388,608 B  layer-1 h, scan layout
  short* xcT0 = (short*)(ws + 8388608);    // 8,388,608 B  Xc0 scan layout
  short* a0   = (short*)(ws + 16777216);   //   524,288 B  W0@Wemb  [256,1024]
  short* a1   = (short*)(ws + 17301504);   //   131,072 B  W1@V0    [256,256]
  short* a2   = (short*)(ws + 17432576);   //   524,288 B  Wout@V1  [1024,256]

  // a0/a1/a2 straight from f32 inputs (prep eliminated)
  wgemm<<<36, 256, 0, stream>>>(wemb, wf, vfp, wout, a0, a1, a2);

  // Xc0 = x(f32) @ a0^T -> scan layout
  gemm_x<<<512, 256, 0, stream>>>(xf, a0, xcT0);

  // both RNN layers, one chained kernel (xc1 stays on-chip)
  scan2<<<256, 256, 0, stream>>>(ufp, a1, xcT0, hbuf, hs);

  // probs = softmax_T(h1 @ a2^T), fused
  gemm_logsm<<<512, 256, 0, stream>>>(hbuf, a2, (float*)d_out);
}

// Round 5
// 269.872 us; speedup vs baseline: 1.3372x; 1.3372x over previous
//
#include <hip/hip_runtime.h>
#include <stdint.h>
#include <stddef.h>

// ---------- types ----------
typedef short s8v __attribute__((ext_vector_type(8)));   // 8 bf16 (4 VGPRs) MFMA A/B frag
typedef short s4v __attribute__((ext_vector_type(4)));   // 4 bf16
typedef float f4v __attribute__((ext_vector_type(4)));   // MFMA C/D frag

#define DEV static __device__ __forceinline__

// Problem constants: B=32 T=512 VOCAB=1024 D=256 H=256 O=1024 L=2
// Pipeline (5 dispatches):
//   wgemm : a0 = W0@Wemb, a1 = W1@V0, a2 = Wout@V1  (straight from f32 inputs)
//   gemm_x: Xc0 = x(f32) @ a0^T -> scan layout
//   scan_fuse: layer-0 recurrence + Xc1 = h0 @ a1^T fused
//   scan_rnn : layer-1 recurrence
//   gemm_logsm: softmax_T(h1 @ a2^T) fused

DEV short f2b(float f) {
  union { float f; uint32_t u; } v; v.f = f;
  uint32_t u = v.u;
  uint32_t r = (u + 0x7fffu + ((u >> 16) & 1u)) >> 16;   // RNE
  return (short)(uint16_t)r;
}
DEV float b2f(short h) {
  union { uint32_t u; float f; } v; v.u = ((uint32_t)(uint16_t)h) << 16;
  return v.f;
}

DEV void gl_lds16(const void* g, void* l) {
  __builtin_amdgcn_global_load_lds(
      (__attribute__((address_space(1))) void*)(uintptr_t)(g),
      (__attribute__((address_space(3))) void*)(l), 16, 0, 0);
}

// scan layout row remap: m = b*512 + t  ->  ((g*512 + t)*16 + s), g=b>>4, s=b&15
DEV int rmap_scan(int m) {
  int b = m >> 9;
  int t = m & 511;
  return ((((b >> 4) << 9) | t) << 4) | (b & 15);
}

// conflict-free hT layout: hT[s][k] stored at [kb][q][s][j], k = kb*32 + q*8 + j.
// B-frag ds_read_b128 (lane sid,quad; kb): offset = kb*512 + quad*128 + sid*8
//  -> lane offsets 8*(16*quad+sid) = 8*(0..63): contiguous 1KB, ZERO bank conflict.
DEV int hoff(int s, int k) {
  return ((k >> 5) << 9) + (((k >> 3) & 3) << 7) + (s << 3) + (k & 7);
}

// ---------- weight-product GEMMs straight from f32 ----------
// C[m,n] = sum_k A[m,k] * Bsrc[k,n]  (Bsrc consumed transposed at frag-build time).
DEV void wgemm_body(const float* __restrict__ Af, const float* __restrict__ Bsrc,
                    short* __restrict__ C, int lda, int ldbs, int ldc,
                    int m0, int n0, int tid, short* As, float* Bf) {
  const int w = tid >> 6, lane = tid & 63, quad = lane >> 4, sid = lane & 15;
  const int wm = (w >> 1) * 64, wn = (w & 1) * 64;

  f4v acc[4][4];
#pragma unroll
  for (int i = 0; i < 4; ++i)
#pragma unroll
    for (int j = 0; j < 4; ++j) acc[i][j] = (f4v){0.f, 0.f, 0.f, 0.f};

  for (int k0 = 0; k0 < 256; k0 += 64) {
    // B: 64 k-rows x 128 n f32, linear direct-to-LDS
#pragma unroll
    for (int q = 0; q < 8; ++q) {
      int lin = q * 256 + tid;
      int kr = lin >> 5, nc = (lin & 31) << 2;
      gl_lds16(Bsrc + (size_t)(k0 + kr) * ldbs + n0 + nc, &Bf[lin << 2]);
    }
    // A: 128 rows x 64 k f32 -> bf16, pitch 72
#pragma unroll
    for (int q = 0; q < 4; ++q) {
      int lin = q * 256 + tid;
      int row = lin >> 3, kc = (lin & 7) << 3;
      const float* ap = Af + (size_t)(m0 + row) * lda + k0 + kc;
      float4 v0 = *(const float4*)ap;
      float4 v1 = *(const float4*)(ap + 4);
      s8v p;
      p[0] = f2b(v0.x); p[1] = f2b(v0.y); p[2] = f2b(v0.z); p[3] = f2b(v0.w);
      p[4] = f2b(v1.x); p[5] = f2b(v1.y); p[6] = f2b(v1.z); p[7] = f2b(v1.w);
      *(s8v*)&As[row * 72 + kc] = p;
    }
    __syncthreads();
#pragma unroll
    for (int kb = 0; kb < 2; ++kb) {
      s8v af[4], bf[4];
#pragma unroll
      for (int mt = 0; mt < 4; ++mt)
        af[mt] = *(const s8v*)&As[(wm + 16 * mt + sid) * 72 + kb * 32 + quad * 8];
#pragma unroll
      for (int nt = 0; nt < 4; ++nt) {
        s8v b;
#pragma unroll
        for (int j = 0; j < 8; ++j)
          b[j] = f2b(Bf[(kb * 32 + quad * 8 + j) * 128 + wn + 16 * nt + sid]);
        bf[nt] = b;
      }
#pragma unroll
      for (int mt = 0; mt < 4; ++mt)
#pragma unroll
        for (int nt = 0; nt < 4; ++nt)
          acc[mt][nt] = __builtin_amdgcn_mfma_f32_16x16x32_bf16(af[mt], bf[nt], acc[mt][nt], 0, 0, 0);
    }
    __syncthreads();
  }
#pragma unroll
  for (int mt = 0; mt < 4; ++mt)
#pragma unroll
    for (int r = 0; r < 4; ++r) {
      int gm = m0 + wm + 16 * mt + 4 * quad + r;
      size_t ro = (size_t)gm * ldc;
#pragma unroll
      for (int nt = 0; nt < 4; ++nt)
        C[ro + n0 + wn + 16 * nt + sid] = f2b(acc[mt][nt][r]);
    }
}

__global__ __launch_bounds__(256) void wgemm(const float* __restrict__ wemb,
                                             const float* __restrict__ wf,
                                             const float* __restrict__ vfp,
                                             const float* __restrict__ wout,
                                             short* __restrict__ a0,
                                             short* __restrict__ a1,
                                             short* __restrict__ a2) {
  __shared__ __align__(16) short As[128 * 72];   // 18 KB
  __shared__ __align__(16) float Bf[64 * 128];   // 32 KB
  const int blk = blockIdx.x, tid = threadIdx.x;
  if (blk < 16) {          // a0 = W0 @ Wemb : [256,1024], 2x8 tiles
    wgemm_body(wf, wemb, a0, 256, 1024, 1024,
               (blk >> 3) * 128, (blk & 7) * 128, tid, As, Bf);
  } else if (blk < 20) {   // a1 = W1 @ V0 : [256,256], 2x2 tiles
    int b = blk - 16;
    wgemm_body(wf + 65536, vfp, a1, 256, 256, 256,
               (b >> 1) * 128, (b & 1) * 128, tid, As, Bf);
  } else {                 // a2 = Wout @ V1 : [1024,256], 8x2 tiles
    int b = blk - 20;
    wgemm_body(wout, vfp + 65536, a2, 256, 256, 256,
               (b >> 1) * 128, (b & 1) * 128, tid, As, Bf);
  }
}

// ---------- Xc0 = x(f32) @ A0^T, LDS-staged, BM=32 x BN=256, 2 blocks/CU ----------
__global__ __launch_bounds__(256, 2) void gemm_x(const float* __restrict__ Xf,
                                                 const short* __restrict__ Bw,
                                                 short* __restrict__ C) {
  __shared__ __align__(16) short As[32 * 72];    // 4.5 KB (pitch 72 -> 2-way banks)
  __shared__ __align__(16) short Bs[256 * 64];   // 32 KB
  const int tid = threadIdx.x;
  const int w = tid >> 6, lane = tid & 63, quad = lane >> 4, sid = lane & 15;
  const int m0 = blockIdx.x * 32;
  const int wn = w * 64;

  f4v acc[2][4];
#pragma unroll
  for (int i = 0; i < 2; ++i)
#pragma unroll
    for (int j = 0; j < 4; ++j) acc[i][j] = (f4v){0.f, 0.f, 0.f, 0.f};

  for (int k0 = 0; k0 < 1024; k0 += 64) {
#pragma unroll
    for (int q = 0; q < 8; ++q) {
      int lin = q * 256 + tid;
      gl_lds16(Bw + (size_t)(lin >> 3) * 1024 + k0 + ((lin & 7) << 3), &Bs[lin << 3]);
    }
    {
      int row = tid >> 3, kc = (tid & 7) << 3;
      const float* ap = &Xf[(size_t)(m0 + row) * 1024 + k0 + kc];
      float4 v0 = *(const float4*)ap;
      float4 v1 = *(const float4*)(ap + 4);
      s8v p;
      p[0] = f2b(v0.x); p[1] = f2b(v0.y); p[2] = f2b(v0.z); p[3] = f2b(v0.w);
      p[4] = f2b(v1.x); p[5] = f2b(v1.y); p[6] = f2b(v1.z); p[7] = f2b(v1.w);
      *(s8v*)&As[row * 72 + kc] = p;
    }
    __syncthreads();
#pragma unroll
    for (int kb = 0; kb < 2; ++kb) {
      s8v af[2], bf[4];
#pragma unroll
      for (int mt = 0; mt < 2; ++mt)
        af[mt] = *(const s8v*)&As[(16 * mt + sid) * 72 + kb * 32 + quad * 8];
#pragma unroll
      for (int nt = 0; nt < 4; ++nt)
        bf[nt] = *(const s8v*)&Bs[(wn + 16 * nt + sid) * 64 + kb * 32 + quad * 8];
#pragma unroll
      for (int mt = 0; mt < 2; ++mt)
#pragma unroll
        for (int nt = 0; nt < 4; ++nt)
          acc[mt][nt] = __builtin_amdgcn_mfma_f32_16x16x32_bf16(af[mt], bf[nt], acc[mt][nt], 0, 0, 0);
    }
    __syncthreads();
  }

#pragma unroll
  for (int mt = 0; mt < 2; ++mt)
#pragma unroll
    for (int r = 0; r < 4; ++r) {
      int gm = m0 + 16 * mt + 4 * quad + r;
      size_t ro = (size_t)rmap_scan(gm) * 256;
#pragma unroll
      for (int nt = 0; nt < 4; ++nt)
        C[ro + wn + 16 * nt + sid] = f2b(acc[mt][nt][r]);
    }
}

// ---------- layer-0 scan fused with Xc1 = h0 @ A1^T ----------
// CL=4 -> 256 blocks; 17-step path; one barrier/step (double-buffered hT).
// U0 converted from f32 at init. Conflict-free hT layout + xc register prefetch.
__global__ __launch_bounds__(256, 1) void scan_fuse(const float* __restrict__ Uf,
                                                    const short* __restrict__ A1b,
                                                    const short* __restrict__ XcIn,
                                                    short* __restrict__ XcOut,
                                                    const float* __restrict__ hinit) {
  constexpr int CL = 4, WU = 12, NC = 128;
  __shared__ __align__(16) short hT[2][4096];
  const int tid = threadIdx.x;
  const int w = tid >> 6, lane = tid & 63, quad = lane >> 4, sid = lane & 15;
  const int c = blockIdx.x & (NC - 1);
  const int g = blockIdx.x >> 7;

  s8v uf[4][8], vf[4][8];
#pragma unroll
  for (int mt = 0; mt < 4; ++mt)
#pragma unroll
    for (int kb = 0; kb < 8; ++kb) {
      int i = 64 * w + 16 * mt + sid;
      int k = 32 * kb + quad * 8;
      const float* u0 = Uf + (size_t)i * 256 + k;
      float4 a = *(const float4*)u0, b = *(const float4*)(u0 + 4);
      s8v p;
      p[0] = f2b(a.x); p[1] = f2b(a.y); p[2] = f2b(a.z); p[3] = f2b(a.w);
      p[4] = f2b(b.x); p[5] = f2b(b.y); p[6] = f2b(b.z); p[7] = f2b(b.w);
      uf[mt][kb] = p;
      vf[mt][kb] = *(const s8v*)&A1b[i * 256 + k];
    }

  const int t0 = (c * CL <= WU) ? 0 : c * CL - WU;
  const int t1 = (c + 1) * CL;

  for (int idx = tid; idx < 4096; idx += 256) {
    int s = idx >> 8, i = idx & 255;
    hT[0][hoff(s, i)] = (t0 == 0) ? f2b(hinit[i]) : (short)0;
  }
  __syncthreads();

  // prefetch xc for t0
  s4v xcn[4];
  {
    const int xb = (((g << 9) + t0) * 16 + sid) * 256;
#pragma unroll
    for (int mt = 0; mt < 4; ++mt)
      xcn[mt] = *(const s4v*)&XcIn[xb + 64 * w + 16 * mt + 4 * quad];
  }

  int pr = 0;
  for (int t = t0; t <= t1; ++t) {
    s8v bf[8];
#pragma unroll
    for (int kb = 0; kb < 8; ++kb)
      bf[kb] = *(const s8v*)&hT[pr][kb * 512 + quad * 128 + sid * 8];
    const bool doh = (t < t1);
    s4v xcc[4];
    if (doh) {
#pragma unroll
      for (int mt = 0; mt < 4; ++mt) xcc[mt] = xcn[mt];
    }
    if (t + 1 < t1) {   // issue next step's xc loads (hidden under MFMA passes)
      const int xb = (((g << 9) + (t + 1)) * 16 + sid) * 256;
#pragma unroll
      for (int mt = 0; mt < 4; ++mt)
        xcn[mt] = *(const s4v*)&XcIn[xb + 64 * w + 16 * mt + 4 * quad];
    }

    if (t > c * CL) {  // emit xc1_{t-1} = h_{t-1} @ A1^T (owned, warmed rows only)
      f4v ax[4];
#pragma unroll
      for (int mt = 0; mt < 4; ++mt) ax[mt] = (f4v){0.f, 0.f, 0.f, 0.f};
#pragma unroll
      for (int kb = 0; kb < 8; ++kb)
#pragma unroll
        for (int mt = 0; mt < 4; ++mt)
          ax[mt] = __builtin_amdgcn_mfma_f32_16x16x32_bf16(vf[mt][kb], bf[kb], ax[mt], 0, 0, 0);
      const int obase = (((g << 9) + (t - 1)) * 16 + sid) * 256;
#pragma unroll
      for (int mt = 0; mt < 4; ++mt) {
        s4v p; p.x = f2b(ax[mt].x); p.y = f2b(ax[mt].y);
        p.z = f2b(ax[mt].z); p.w = f2b(ax[mt].w);
        *(s4v*)&XcOut[obase + 64 * w + 16 * mt + 4 * quad] = p;
      }
    }

    if (doh) {
      f4v acc[4];
#pragma unroll
      for (int mt = 0; mt < 4; ++mt) acc[mt] = (f4v){0.f, 0.f, 0.f, 0.f};
#pragma unroll
      for (int kb = 0; kb < 8; ++kb)
#pragma unroll
        for (int mt = 0; mt < 4; ++mt)
          acc[mt] = __builtin_amdgcn_mfma_f32_16x16x32_bf16(uf[mt][kb], bf[kb], acc[mt], 0, 0, 0);
#pragma unroll
      for (int mt = 0; mt < 4; ++mt) {
        int k0 = 64 * w + 16 * mt + 4 * quad;
        f4v v = acc[mt];
        v.x += b2f(xcc[mt].x); v.y += b2f(xcc[mt].y);
        v.z += b2f(xcc[mt].z); v.w += b2f(xcc[mt].w);
        s4v p; p.x = f2b(v.x); p.y = f2b(v.y); p.z = f2b(v.z); p.w = f2b(v.w);
        *(s4v*)&hT[pr ^ 1][hoff(sid, k0)] = p;
      }
    }
    pr ^= 1;
    __syncthreads();
  }
}

// ---------- chunked recurrence scan (layer 1) ----------
// CL=2 -> 512 blocks -> 2 blocks/CU; U1 converted from f32 at init.
__global__ __launch_bounds__(256, 2) void scan_rnn(const float* __restrict__ Uf,
                                                   const short* __restrict__ XcT,
                                                   short* __restrict__ hbuf,
                                                   const float* __restrict__ hinit) {
  constexpr int CL = 2, WU = 12, NC = 256;
  __shared__ __align__(16) short hT[2][4096];
  const int tid = threadIdx.x;
  const int w = tid >> 6, lane = tid & 63, quad = lane >> 4, sid = lane & 15;
  const int c = blockIdx.x & (NC - 1);
  const int g = blockIdx.x >> 8;

  s8v uf[4][8];
#pragma unroll
  for (int mt = 0; mt < 4; ++mt)
#pragma unroll
    for (int kb = 0; kb < 8; ++kb) {
      int i = 64 * w + 16 * mt + sid;
      int k = 32 * kb + quad * 8;
      const float* u1 = Uf + (size_t)i * 256 + k;
      float4 a = *(const float4*)u1, b = *(const float4*)(u1 + 4);
      s8v p;
      p[0] = f2b(a.x); p[1] = f2b(a.y); p[2] = f2b(a.z); p[3] = f2b(a.w);
      p[4] = f2b(b.x); p[5] = f2b(b.y); p[6] = f2b(b.z); p[7] = f2b(b.w);
      uf[mt][kb] = p;
    }

  const int t0 = (c * CL <= WU) ? 0 : c * CL - WU;
  const int t1 = (c + 1) * CL;

  for (int idx = tid; idx < 4096; idx += 256) {
    int s = idx >> 8, i = idx & 255;
    hT[0][hoff(s, i)] = (t0 == 0) ? f2b(hinit[i]) : (short)0;
  }
  __syncthreads();

  s4v xcn[4];
  {
    const int xb = (((g << 9) + t0) * 16 + sid) * 256;
#pragma unroll
    for (int mt = 0; mt < 4; ++mt)
      xcn[mt] = *(const s4v*)&XcT[xb + 64 * w + 16 * mt + 4 * quad];
  }

  int pr = 0;
  for (int t = t0; t < t1; ++t) {
    s8v bf[8];
#pragma unroll
    for (int kb = 0; kb < 8; ++kb)
      bf[kb] = *(const s8v*)&hT[pr][kb * 512 + quad * 128 + sid * 8];
    s4v xcc[4];
#pragma unroll
    for (int mt = 0; mt < 4; ++mt) xcc[mt] = xcn[mt];
    if (t + 1 < t1) {
      const int xb = (((g << 9) + (t + 1)) * 16 + sid) * 256;
#pragma unroll
      for (int mt = 0; mt < 4; ++mt)
        xcn[mt] = *(const s4v*)&XcT[xb + 64 * w + 16 * mt + 4 * quad];
    }

    f4v acc[4];
#pragma unroll
    for (int mt = 0; mt < 4; ++mt) acc[mt] = (f4v){0.f, 0.f, 0.f, 0.f};
#pragma unroll
    for (int kb = 0; kb < 8; ++kb)
#pragma unroll
      for (int mt = 0; mt < 4; ++mt)
        acc[mt] = __builtin_amdgcn_mfma_f32_16x16x32_bf16(uf[mt][kb], bf[kb], acc[mt], 0, 0, 0);

    const bool emit = (t >= c * CL);
    const int xbase = (((g << 9) + t) * 16 + sid) * 256;
#pragma unroll
    for (int mt = 0; mt < 4; ++mt) {
      int k0 = 64 * w + 16 * mt + 4 * quad;
      f4v v = acc[mt];
      v.x += b2f(xcc[mt].x); v.y += b2f(xcc[mt].y);
      v.z += b2f(xcc[mt].z); v.w += b2f(xcc[mt].w);
      s4v p; p.x = f2b(v.x); p.y = f2b(v.y); p.z = f2b(v.z); p.w = f2b(v.w);
      *(s4v*)&hT[pr ^ 1][hoff(sid, k0)] = p;
      if (emit) *(s4v*)&hbuf[xbase + k0] = p;
    }
    pr ^= 1;
    __syncthreads();
  }
}

// ---------- fused logits GEMM + softmax over T ----------
__global__ __launch_bounds__(256, 2) void gemm_logsm(const short* __restrict__ A,
                                                     const short* __restrict__ Bw,
                                                     float* __restrict__ out) {
  __shared__ __align__(16) short As[512 * 40];   // [t][k-local 32, pitch 40]
  __shared__ __align__(16) short Bs[64 * 32];    // [kch 0..3][row 0..63] of 8 shorts
  __shared__ float2 red[4][64];                  // per-wave (max,sum) per col
  const int tid = threadIdx.x;
  const int w = tid >> 6, lane = tid & 63, quad = lane >> 4, sid = lane & 15;
  const int b = blockIdx.x & 31, ot = blockIdx.x >> 5;
  const int g = b >> 4, si = b & 15;

  f4v acc[8][4];
#pragma unroll
  for (int i = 0; i < 8; ++i)
#pragma unroll
    for (int j = 0; j < 4; ++j) acc[i][j] = (f4v){0.f, 0.f, 0.f, 0.f};

  for (int k0 = 0; k0 < 256; k0 += 32) {
#pragma unroll
    for (int q = 0; q < 8; ++q) {
      int lin = q * 256 + tid;
      int t = lin >> 2, kch = lin & 3;
      size_t ar = ((size_t)(g * 512 + t) * 16 + si) * 256;
      s8v v = *(const s8v*)(A + ar + k0 + kch * 8);
      *(s8v*)&As[t * 40 + kch * 8] = v;
    }
    {
      int row = tid & 63, kch = tid >> 6;
      s8v v = *(const s8v*)(Bw + (size_t)(ot * 64 + row) * 256 + k0 + kch * 8);
      *(s8v*)&Bs[tid << 3] = v;
    }
    __syncthreads();
    s8v bf[4];
#pragma unroll
    for (int nt = 0; nt < 4; ++nt)
      bf[nt] = *(const s8v*)&Bs[(quad * 64 + 16 * nt + sid) * 8];
#pragma unroll
    for (int mt = 0; mt < 8; ++mt) {
      s8v af = *(const s8v*)&As[(128 * w + 16 * mt + sid) * 40 + quad * 8];
#pragma unroll
      for (int nt = 0; nt < 4; ++nt)
        acc[mt][nt] = __builtin_amdgcn_mfma_f32_16x16x32_bf16(af, bf[nt], acc[mt][nt], 0, 0, 0);
    }
    __syncthreads();
  }

#pragma unroll
  for (int nt = 0; nt < 4; ++nt) {
    float m = -3.0e38f;
#pragma unroll
    for (int mt = 0; mt < 8; ++mt)
#pragma unroll
      for (int r = 0; r < 4; ++r) m = fmaxf(m, acc[mt][nt][r]);
    float sum = 0.f;
#pragma unroll
    for (int mt = 0; mt < 8; ++mt)
#pragma unroll
      for (int r = 0; r < 4; ++r) sum += __expf(acc[mt][nt][r] - m);
#pragma unroll
    for (int d = 16; d < 64; d <<= 1) {
      float om = __shfl_xor(m, d, 64);
      float os = __shfl_xor(sum, d, 64);
      float nm = fmaxf(m, om);
      sum = sum * __expf(m - nm) + os * __expf(om - nm);
      m = nm;
    }
    if (quad == 0) red[w][16 * nt + sid] = (float2){m, sum};
  }
  __syncthreads();
#pragma unroll
  for (int nt = 0; nt < 4; ++nt) {
    float M = -3.0e38f, S = 0.f;
#pragma unroll
    for (int ww = 0; ww < 4; ++ww) {
      float2 r2 = red[ww][16 * nt + sid];
      float nm = fmaxf(M, r2.x);
      S = S * __expf(M - nm) + r2.y * __expf(r2.x - nm);
      M = nm;
    }
    const float inv = 1.0f / S;
    const size_t cbase = (size_t)b * 512 * 1024 + ot * 64 + 16 * nt + sid;
#pragma unroll
    for (int mt = 0; mt < 8; ++mt)
#pragma unroll
      for (int r = 0; r < 4; ++r) {
        int t = 128 * w + 16 * mt + 4 * quad + r;
        out[cbase + (size_t)t * 1024] = __expf(acc[mt][nt][r] - M) * inv;
      }
  }
}

// ---------- host ----------
extern "C" void kernel_launch(void* const* d_in, const int* in_sizes, int n_in,
                              void* d_out, int out_size, void* d_ws, size_t ws_size,
                              hipStream_t stream) {
  (void)in_sizes; (void)n_in; (void)out_size; (void)ws_size;
  const float* xf   = (const float*)d_in[0];
  const float* hs   = (const float*)d_in[1];
  const float* wemb = (const float*)d_in[2];
  const float* wf   = (const float*)d_in[3];
  const float* ufp  = (const float*)d_in[4];
  const float* vfp  = (const float*)d_in[5];
  const float* wout = (const float*)d_in[6];

  char* ws = (char*)d_ws;
  short* hbuf = (short*)(ws);              // 8,388,608 B  layer-1 h, scan layout
  short* xcT0 = (short*)(ws + 8388608);    // 8,388,608 B  Xc0 scan layout
  short* xcT1 = (short*)(ws + 16777216);   // 8,388,608 B  Xc1 scan layout
  short* a0   = (short*)(ws + 25165824);   //   524,288 B  W0@Wemb  [256,1024]
  short* a1   = (short*)(ws + 25690112);   //   131,072 B  W1@V0    [256,256]
  short* a2   = (short*)(ws + 25821184);   //   524,288 B  Wout@V1  [1024,256]

  // a0/a1/a2 straight from f32 inputs
  wgemm<<<36, 256, 0, stream>>>(wemb, wf, vfp, wout, a0, a1, a2);

  // Xc0 = x(f32) @ a0^T -> scan layout
  gemm_x<<<512, 256, 0, stream>>>(xf, a0, xcT0);

  // layer-0 scan, Xc1 = h0 @ a1^T fused into the step epilogue
  scan_fuse<<<256, 256, 0, stream>>>(ufp, a1, xcT0, xcT1, hs);

  // layer-1 scan
  scan_rnn<<<512, 256, 0, stream>>>(ufp + 65536, xcT1, hbuf, hs + 256);

  // probs = softmax_T(h1 @ a2^T), fused
  gemm_logsm<<<512, 256, 0, stream>>>(hbuf, a2, (float*)d_out);
}

// Round 6
// 234.982 us; speedup vs baseline: 1.5358x; 1.1485x over previous
//
#include <hip/hip_runtime.h>
#include <stdint.h>
#include <stddef.h>

// ---------- types ----------
typedef short s8v __attribute__((ext_vector_type(8)));   // 8 bf16 (4 VGPRs) MFMA A/B frag
typedef short s4v __attribute__((ext_vector_type(4)));   // 4 bf16
typedef float f4v __attribute__((ext_vector_type(4)));   // MFMA C/D frag

#define DEV static __device__ __forceinline__

// Problem constants: B=32 T=512 VOCAB=1024 D=256 H=256 O=1024 L=2
// Pipeline (5 dispatches):
//   wgemm : a0 = W0@Wemb, a1 = W1@V0, a2 = Wout@V1 (f32 inputs) + U->bf16 (4 blocks)
//   gemm_x: Xc0 = x(f32) @ a0^T -> scan layout
//   scan_fuse: layer-0 recurrence + Xc1 = h0 @ a1^T fused
//   scan_rnn : layer-1 recurrence
//   gemm_logsm: softmax_T(h1 @ a2^T) fused

DEV short f2b(float f) {
  union { float f; uint32_t u; } v; v.f = f;
  uint32_t u = v.u;
  uint32_t r = (u + 0x7fffu + ((u >> 16) & 1u)) >> 16;   // RNE
  return (short)(uint16_t)r;
}
DEV float b2f(short h) {
  union { uint32_t u; float f; } v; v.u = ((uint32_t)(uint16_t)h) << 16;
  return v.f;
}

DEV void gl_lds16(const void* g, void* l) {
  __builtin_amdgcn_global_load_lds(
      (__attribute__((address_space(1))) void*)(uintptr_t)(g),
      (__attribute__((address_space(3))) void*)(l), 16, 0, 0);
}

// scan layout row remap: m = b*512 + t  ->  ((g*512 + t)*16 + s), g=b>>4, s=b&15
DEV int rmap_scan(int m) {
  int b = m >> 9;
  int t = m & 511;
  return ((((b >> 4) << 9) | t) << 4) | (b & 15);
}

// conflict-free hT layout: hT[s][k] stored at [kb][q][s][j], k = kb*32 + q*8 + j.
// B-frag ds_read_b128 (lane sid,quad; kb): offset = kb*512 + quad*128 + sid*8
//  -> lane offsets 8*(16*quad+sid) = 8*(0..63): contiguous 1KB.
DEV int hoff(int s, int k) {
  return ((k >> 5) << 9) + (((k >> 3) & 3) << 7) + (s << 3) + (k & 7);
}

// ---------- weight-product GEMMs straight from f32 + U bf16 convert ----------
// C[m,n] = sum_k A[m,k] * Bsrc[k,n]  (Bsrc consumed transposed at frag-build time).
DEV void wgemm_body(const float* __restrict__ Af, const float* __restrict__ Bsrc,
                    short* __restrict__ C, int lda, int ldbs, int ldc,
                    int m0, int n0, int tid, short* As, float* Bf) {
  const int w = tid >> 6, lane = tid & 63, quad = lane >> 4, sid = lane & 15;
  const int wm = (w >> 1) * 64, wn = (w & 1) * 64;

  f4v acc[4][4];
#pragma unroll
  for (int i = 0; i < 4; ++i)
#pragma unroll
    for (int j = 0; j < 4; ++j) acc[i][j] = (f4v){0.f, 0.f, 0.f, 0.f};

  for (int k0 = 0; k0 < 256; k0 += 64) {
    // B: 64 k-rows x 128 n f32, linear direct-to-LDS
#pragma unroll
    for (int q = 0; q < 8; ++q) {
      int lin = q * 256 + tid;
      int kr = lin >> 5, nc = (lin & 31) << 2;
      gl_lds16(Bsrc + (size_t)(k0 + kr) * ldbs + n0 + nc, &Bf[lin << 2]);
    }
    // A: 128 rows x 64 k f32 -> bf16, pitch 72
#pragma unroll
    for (int q = 0; q < 4; ++q) {
      int lin = q * 256 + tid;
      int row = lin >> 3, kc = (lin & 7) << 3;
      const float* ap = Af + (size_t)(m0 + row) * lda + k0 + kc;
      float4 v0 = *(const float4*)ap;
      float4 v1 = *(const float4*)(ap + 4);
      s8v p;
      p[0] = f2b(v0.x); p[1] = f2b(v0.y); p[2] = f2b(v0.z); p[3] = f2b(v0.w);
      p[4] = f2b(v1.x); p[5] = f2b(v1.y); p[6] = f2b(v1.z); p[7] = f2b(v1.w);
      *(s8v*)&As[row * 72 + kc] = p;
    }
    __syncthreads();
#pragma unroll
    for (int kb = 0; kb < 2; ++kb) {
      s8v af[4], bf[4];
#pragma unroll
      for (int mt = 0; mt < 4; ++mt)
        af[mt] = *(const s8v*)&As[(wm + 16 * mt + sid) * 72 + kb * 32 + quad * 8];
#pragma unroll
      for (int nt = 0; nt < 4; ++nt) {
        s8v b;
#pragma unroll
        for (int j = 0; j < 8; ++j)
          b[j] = f2b(Bf[(kb * 32 + quad * 8 + j) * 128 + wn + 16 * nt + sid]);
        bf[nt] = b;
      }
#pragma unroll
      for (int mt = 0; mt < 4; ++mt)
#pragma unroll
        for (int nt = 0; nt < 4; ++nt)
          acc[mt][nt] = __builtin_amdgcn_mfma_f32_16x16x32_bf16(af[mt], bf[nt], acc[mt][nt], 0, 0, 0);
    }
    __syncthreads();
  }
#pragma unroll
  for (int mt = 0; mt < 4; ++mt)
#pragma unroll
    for (int r = 0; r < 4; ++r) {
      int gm = m0 + wm + 16 * mt + 4 * quad + r;
      size_t ro = (size_t)gm * ldc;
#pragma unroll
      for (int nt = 0; nt < 4; ++nt)
        C[ro + n0 + wn + 16 * nt + sid] = f2b(acc[mt][nt][r]);
    }
}

__global__ __launch_bounds__(256) void wgemm(const float* __restrict__ wemb,
                                             const float* __restrict__ wf,
                                             const float* __restrict__ vfp,
                                             const float* __restrict__ wout,
                                             const float* __restrict__ ufp,
                                             short* __restrict__ a0,
                                             short* __restrict__ a1,
                                             short* __restrict__ a2,
                                             short* __restrict__ ub) {
  __shared__ __align__(16) short As[128 * 72];   // 18 KB
  __shared__ __align__(16) float Bf[64 * 128];   // 32 KB
  const int blk = blockIdx.x, tid = threadIdx.x;
  if (blk < 16) {          // a0 = W0 @ Wemb : [256,1024], 2x8 tiles
    wgemm_body(wf, wemb, a0, 256, 1024, 1024,
               (blk >> 3) * 128, (blk & 7) * 128, tid, As, Bf);
  } else if (blk < 20) {   // a1 = W1 @ V0 : [256,256], 2x2 tiles
    int b = blk - 16;
    wgemm_body(wf + 65536, vfp, a1, 256, 256, 256,
               (b >> 1) * 128, (b & 1) * 128, tid, As, Bf);
  } else if (blk < 36) {   // a2 = Wout @ V1 : [1024,256], 8x2 tiles
    int b = blk - 20;
    wgemm_body(wout, vfp + 65536, a2, 256, 256, 256,
               (b >> 1) * 128, (b & 1) * 128, tid, As, Bf);
  } else {                 // blk 36..39: U (2 layers, 512 KB f32) -> bf16 once
    int b = blk - 36;      // each block: 32768 floats = 8192 float4
    const float* src = ufp + (size_t)b * 32768;
    short* dst = ub + (size_t)b * 32768;
#pragma unroll 4
    for (int i = tid; i < 8192; i += 256) {
      float4 v = ((const float4*)src)[i];
      s4v q; q.x = f2b(v.x); q.y = f2b(v.y); q.z = f2b(v.z); q.w = f2b(v.w);
      ((s4v*)dst)[i] = q;
    }
  }
}

// ---------- Xc0 = x(f32) @ A0^T, LDS-staged, BM=32 x BN=256, 2 blocks/CU ----------
__global__ __launch_bounds__(256, 2) void gemm_x(const float* __restrict__ Xf,
                                                 const short* __restrict__ Bw,
                                                 short* __restrict__ C) {
  __shared__ __align__(16) short As[32 * 72];    // 4.5 KB (pitch 72 -> 2-way banks)
  __shared__ __align__(16) short Bs[256 * 64];   // 32 KB
  const int tid = threadIdx.x;
  const int w = tid >> 6, lane = tid & 63, quad = lane >> 4, sid = lane & 15;
  const int m0 = blockIdx.x * 32;
  const int wn = w * 64;

  f4v acc[2][4];
#pragma unroll
  for (int i = 0; i < 2; ++i)
#pragma unroll
    for (int j = 0; j < 4; ++j) acc[i][j] = (f4v){0.f, 0.f, 0.f, 0.f};

  for (int k0 = 0; k0 < 1024; k0 += 64) {
#pragma unroll
    for (int q = 0; q < 8; ++q) {
      int lin = q * 256 + tid;
      gl_lds16(Bw + (size_t)(lin >> 3) * 1024 + k0 + ((lin & 7) << 3), &Bs[lin << 3]);
    }
    {
      int row = tid >> 3, kc = (tid & 7) << 3;
      const float* ap = &Xf[(size_t)(m0 + row) * 1024 + k0 + kc];
      float4 v0 = *(const float4*)ap;
      float4 v1 = *(const float4*)(ap + 4);
      s8v p;
      p[0] = f2b(v0.x); p[1] = f2b(v0.y); p[2] = f2b(v0.z); p[3] = f2b(v0.w);
      p[4] = f2b(v1.x); p[5] = f2b(v1.y); p[6] = f2b(v1.z); p[7] = f2b(v1.w);
      *(s8v*)&As[row * 72 + kc] = p;
    }
    __syncthreads();
#pragma unroll
    for (int kb = 0; kb < 2; ++kb) {
      s8v af[2], bf[4];
#pragma unroll
      for (int mt = 0; mt < 2; ++mt)
        af[mt] = *(const s8v*)&As[(16 * mt + sid) * 72 + kb * 32 + quad * 8];
#pragma unroll
      for (int nt = 0; nt < 4; ++nt)
        bf[nt] = *(const s8v*)&Bs[(wn + 16 * nt + sid) * 64 + kb * 32 + quad * 8];
#pragma unroll
      for (int mt = 0; mt < 2; ++mt)
#pragma unroll
        for (int nt = 0; nt < 4; ++nt)
          acc[mt][nt] = __builtin_amdgcn_mfma_f32_16x16x32_bf16(af[mt], bf[nt], acc[mt][nt], 0, 0, 0);
    }
    __syncthreads();
  }

#pragma unroll
  for (int mt = 0; mt < 2; ++mt)
#pragma unroll
    for (int r = 0; r < 4; ++r) {
      int gm = m0 + 16 * mt + 4 * quad + r;
      size_t ro = (size_t)rmap_scan(gm) * 256;
#pragma unroll
      for (int nt = 0; nt < 4; ++nt)
        C[ro + wn + 16 * nt + sid] = f2b(acc[mt][nt][r]);
    }
}

// ---------- layer-0 scan fused with Xc1 = h0 @ A1^T ----------
// CL=4 -> 256 blocks; 17-step path; one barrier/step (double-buffered hT).
// U0 loaded as bf16 (converted once in wgemm). Conflict-free hT layout + xc prefetch.
__global__ __launch_bounds__(256, 1) void scan_fuse(const short* __restrict__ Ub,
                                                    const short* __restrict__ A1b,
                                                    const short* __restrict__ XcIn,
                                                    short* __restrict__ XcOut,
                                                    const float* __restrict__ hinit) {
  constexpr int CL = 4, WU = 12, NC = 128;
  __shared__ __align__(16) short hT[2][4096];
  const int tid = threadIdx.x;
  const int w = tid >> 6, lane = tid & 63, quad = lane >> 4, sid = lane & 15;
  const int c = blockIdx.x & (NC - 1);
  const int g = blockIdx.x >> 7;

  s8v uf[4][8], vf[4][8];
#pragma unroll
  for (int mt = 0; mt < 4; ++mt)
#pragma unroll
    for (int kb = 0; kb < 8; ++kb) {
      int i = 64 * w + 16 * mt + sid;
      int k = 32 * kb + quad * 8;
      uf[mt][kb] = *(const s8v*)&Ub[i * 256 + k];
      vf[mt][kb] = *(const s8v*)&A1b[i * 256 + k];
    }

  const int t0 = (c * CL <= WU) ? 0 : c * CL - WU;
  const int t1 = (c + 1) * CL;

  for (int idx = tid; idx < 4096; idx += 256) {
    int s = idx >> 8, i = idx & 255;
    hT[0][hoff(s, i)] = (t0 == 0) ? f2b(hinit[i]) : (short)0;
  }
  __syncthreads();

  // prefetch xc for t0
  s4v xcn[4];
  {
    const int xb = (((g << 9) + t0) * 16 + sid) * 256;
#pragma unroll
    for (int mt = 0; mt < 4; ++mt)
      xcn[mt] = *(const s4v*)&XcIn[xb + 64 * w + 16 * mt + 4 * quad];
  }

  int pr = 0;
  for (int t = t0; t <= t1; ++t) {
    s8v bf[8];
#pragma unroll
    for (int kb = 0; kb < 8; ++kb)
      bf[kb] = *(const s8v*)&hT[pr][kb * 512 + quad * 128 + sid * 8];
    const bool doh = (t < t1);
    s4v xcc[4];
    if (doh) {
#pragma unroll
      for (int mt = 0; mt < 4; ++mt) xcc[mt] = xcn[mt];
    }
    if (t + 1 < t1) {   // issue next step's xc loads (hidden under MFMA passes)
      const int xb = (((g << 9) + (t + 1)) * 16 + sid) * 256;
#pragma unroll
      for (int mt = 0; mt < 4; ++mt)
        xcn[mt] = *(const s4v*)&XcIn[xb + 64 * w + 16 * mt + 4 * quad];
    }

    if (t > c * CL) {  // emit xc1_{t-1} = h_{t-1} @ A1^T (owned, warmed rows only)
      f4v ax[4];
#pragma unroll
      for (int mt = 0; mt < 4; ++mt) ax[mt] = (f4v){0.f, 0.f, 0.f, 0.f};
#pragma unroll
      for (int kb = 0; kb < 8; ++kb)
#pragma unroll
        for (int mt = 0; mt < 4; ++mt)
          ax[mt] = __builtin_amdgcn_mfma_f32_16x16x32_bf16(vf[mt][kb], bf[kb], ax[mt], 0, 0, 0);
      const int obase = (((g << 9) + (t - 1)) * 16 + sid) * 256;
#pragma unroll
      for (int mt = 0; mt < 4; ++mt) {
        s4v p; p.x = f2b(ax[mt].x); p.y = f2b(ax[mt].y);
        p.z = f2b(ax[mt].z); p.w = f2b(ax[mt].w);
        *(s4v*)&XcOut[obase + 64 * w + 16 * mt + 4 * quad] = p;
      }
    }

    if (doh) {
      f4v acc[4];
#pragma unroll
      for (int mt = 0; mt < 4; ++mt) acc[mt] = (f4v){0.f, 0.f, 0.f, 0.f};
#pragma unroll
      for (int kb = 0; kb < 8; ++kb)
#pragma unroll
        for (int mt = 0; mt < 4; ++mt)
          acc[mt] = __builtin_amdgcn_mfma_f32_16x16x32_bf16(uf[mt][kb], bf[kb], acc[mt], 0, 0, 0);
#pragma unroll
      for (int mt = 0; mt < 4; ++mt) {
        int k0 = 64 * w + 16 * mt + 4 * quad;
        f4v v = acc[mt];
        v.x += b2f(xcc[mt].x); v.y += b2f(xcc[mt].y);
        v.z += b2f(xcc[mt].z); v.w += b2f(xcc[mt].w);
        s4v p; p.x = f2b(v.x); p.y = f2b(v.y); p.z = f2b(v.z); p.w = f2b(v.w);
        *(s4v*)&hT[pr ^ 1][hoff(sid, k0)] = p;
      }
    }
    pr ^= 1;
    __syncthreads();
  }
}

// ---------- chunked recurrence scan (layer 1) ----------
// CL=2 -> 512 blocks -> 2 blocks/CU; U1 loaded as bf16.
__global__ __launch_bounds__(256, 2) void scan_rnn(const short* __restrict__ Ub,
                                                   const short* __restrict__ XcT,
                                                   short* __restrict__ hbuf,
                                                   const float* __restrict__ hinit) {
  constexpr int CL = 2, WU = 12, NC = 256;
  __shared__ __align__(16) short hT[2][4096];
  const int tid = threadIdx.x;
  const int w = tid >> 6, lane = tid & 63, quad = lane >> 4, sid = lane & 15;
  const int c = blockIdx.x & (NC - 1);
  const int g = blockIdx.x >> 8;

  s8v uf[4][8];
#pragma unroll
  for (int mt = 0; mt < 4; ++mt)
#pragma unroll
    for (int kb = 0; kb < 8; ++kb) {
      int i = 64 * w + 16 * mt + sid;
      int k = 32 * kb + quad * 8;
      uf[mt][kb] = *(const s8v*)&Ub[i * 256 + k];
    }

  const int t0 = (c * CL <= WU) ? 0 : c * CL - WU;
  const int t1 = (c + 1) * CL;

  for (int idx = tid; idx < 4096; idx += 256) {
    int s = idx >> 8, i = idx & 255;
    hT[0][hoff(s, i)] = (t0 == 0) ? f2b(hinit[i]) : (short)0;
  }
  __syncthreads();

  s4v xcn[4];
  {
    const int xb = (((g << 9) + t0) * 16 + sid) * 256;
#pragma unroll
    for (int mt = 0; mt < 4; ++mt)
      xcn[mt] = *(const s4v*)&XcT[xb + 64 * w + 16 * mt + 4 * quad];
  }

  int pr = 0;
  for (int t = t0; t < t1; ++t) {
    s8v bf[8];
#pragma unroll
    for (int kb = 0; kb < 8; ++kb)
      bf[kb] = *(const s8v*)&hT[pr][kb * 512 + quad * 128 + sid * 8];
    s4v xcc[4];
#pragma unroll
    for (int mt = 0; mt < 4; ++mt) xcc[mt] = xcn[mt];
    if (t + 1 < t1) {
      const int xb = (((g << 9) + (t + 1)) * 16 + sid) * 256;
#pragma unroll
      for (int mt = 0; mt < 4; ++mt)
        xcn[mt] = *(const s4v*)&XcT[xb + 64 * w + 16 * mt + 4 * quad];
    }

    f4v acc[4];
#pragma unroll
    for (int mt = 0; mt < 4; ++mt) acc[mt] = (f4v){0.f, 0.f, 0.f, 0.f};
#pragma unroll
    for (int kb = 0; kb < 8; ++kb)
#pragma unroll
      for (int mt = 0; mt < 4; ++mt)
        acc[mt] = __builtin_amdgcn_mfma_f32_16x16x32_bf16(uf[mt][kb], bf[kb], acc[mt], 0, 0, 0);

    const bool emit = (t >= c * CL);
    const int xbase = (((g << 9) + t) * 16 + sid) * 256;
#pragma unroll
    for (int mt = 0; mt < 4; ++mt) {
      int k0 = 64 * w + 16 * mt + 4 * quad;
      f4v v = acc[mt];
      v.x += b2f(xcc[mt].x); v.y += b2f(xcc[mt].y);
      v.z += b2f(xcc[mt].z); v.w += b2f(xcc[mt].w);
      s4v p; p.x = f2b(v.x); p.y = f2b(v.y); p.z = f2b(v.z); p.w = f2b(v.w);
      *(s4v*)&hT[pr ^ 1][hoff(sid, k0)] = p;
      if (emit) *(s4v*)&hbuf[xbase + k0] = p;
    }
    pr ^= 1;
    __syncthreads();
  }
}

// ---------- fused logits GEMM + softmax over T ----------
__global__ __launch_bounds__(256, 2) void gemm_logsm(const short* __restrict__ A,
                                                     const short* __restrict__ Bw,
                                                     float* __restrict__ out) {
  __shared__ __align__(16) short As[512 * 40];   // [t][k-local 32, pitch 40]
  __shared__ __align__(16) short Bs[64 * 32];    // [kch 0..3][row 0..63] of 8 shorts
  __shared__ float2 red[4][64];                  // per-wave (max,sum) per col
  const int tid = threadIdx.x;
  const int w = tid >> 6, lane = tid & 63, quad = lane >> 4, sid = lane & 15;
  const int b = blockIdx.x & 31, ot = blockIdx.x >> 5;
  const int g = b >> 4, si = b & 15;

  f4v acc[8][4];
#pragma unroll
  for (int i = 0; i < 8; ++i)
#pragma unroll
    for (int j = 0; j < 4; ++j) acc[i][j] = (f4v){0.f, 0.f, 0.f, 0.f};

  for (int k0 = 0; k0 < 256; k0 += 32) {
#pragma unroll
    for (int q = 0; q < 8; ++q) {
      int lin = q * 256 + tid;
      int t = lin >> 2, kch = lin & 3;
      size_t ar = ((size_t)(g * 512 + t) * 16 + si) * 256;
      s8v v = *(const s8v*)(A + ar + k0 + kch * 8);
      *(s8v*)&As[t * 40 + kch * 8] = v;
    }
    {
      int row = tid & 63, kch = tid >> 6;
      s8v v = *(const s8v*)(Bw + (size_t)(ot * 64 + row) * 256 + k0 + kch * 8);
      *(s8v*)&Bs[tid << 3] = v;
    }
    __syncthreads();
    s8v bf[4];
#pragma unroll
    for (int nt = 0; nt < 4; ++nt)
      bf[nt] = *(const s8v*)&Bs[(quad * 64 + 16 * nt + sid) * 8];
#pragma unroll
    for (int mt = 0; mt < 8; ++mt) {
      s8v af = *(const s8v*)&As[(128 * w + 16 * mt + sid) * 40 + quad * 8];
#pragma unroll
      for (int nt = 0; nt < 4; ++nt)
        acc[mt][nt] = __builtin_amdgcn_mfma_f32_16x16x32_bf16(af, bf[nt], acc[mt][nt], 0, 0, 0);
    }
    __syncthreads();
  }

#pragma unroll
  for (int nt = 0; nt < 4; ++nt) {
    float m = -3.0e38f;
#pragma unroll
    for (int mt = 0; mt < 8; ++mt)
#pragma unroll
      for (int r = 0; r < 4; ++r) m = fmaxf(m, acc[mt][nt][r]);
    float sum = 0.f;
#pragma unroll
    for (int mt = 0; mt < 8; ++mt)
#pragma unroll
      for (int r = 0; r < 4; ++r) sum += __expf(acc[mt][nt][r] - m);
#pragma unroll
    for (int d = 16; d < 64; d <<= 1) {
      float om = __shfl_xor(m, d, 64);
      float os = __shfl_xor(sum, d, 64);
      float nm = fmaxf(m, om);
      sum = sum * __expf(m - nm) + os * __expf(om - nm);
      m = nm;
    }
    if (quad == 0) red[w][16 * nt + sid] = (float2){m, sum};
  }
  __syncthreads();
#pragma unroll
  for (int nt = 0; nt < 4; ++nt) {
    float M = -3.0e38f, S = 0.f;
#pragma unroll
    for (int ww = 0; ww < 4; ++ww) {
      float2 r2 = red[ww][16 * nt + sid];
      float nm = fmaxf(M, r2.x);
      S = S * __expf(M - nm) + r2.y * __expf(r2.x - nm);
      M = nm;
    }
    const float inv = 1.0f / S;
    const size_t cbase = (size_t)b * 512 * 1024 + ot * 64 + 16 * nt + sid;
#pragma unroll
    for (int mt = 0; mt < 8; ++mt)
#pragma unroll
      for (int r = 0; r < 4; ++r) {
        int t = 128 * w + 16 * mt + 4 * quad + r;
        out[cbase + (size_t)t * 1024] = __expf(acc[mt][nt][r] - M) * inv;
      }
  }
}

// ---------- host ----------
extern "C" void kernel_launch(void* const* d_in, const int* in_sizes, int n_in,
                              void* d_out, int out_size, void* d_ws, size_t ws_size,
                              hipStream_t stream) {
  (void)in_sizes; (void)n_in; (void)out_size; (void)ws_size;
  const float* xf   = (const float*)d_in[0];
  const float* hs   = (const float*)d_in[1];
  const float* wemb = (const float*)d_in[2];
  const float* wf   = (const float*)d_in[3];
  const float* ufp  = (const float*)d_in[4];
  const float* vfp  = (const float*)d_in[5];
  const float* wout = (const float*)d_in[6];

  char* ws = (char*)d_ws;
  short* hbuf = (short*)(ws);              // 8,388,608 B  layer-1 h, scan layout
  short* xcT0 = (short*)(ws + 8388608);    // 8,388,608 B  Xc0 scan layout
  short* xcT1 = (short*)(ws + 16777216);   // 8,388,608 B  Xc1 scan layout
  short* a0   = (short*)(ws + 25165824);   //   524,288 B  W0@Wemb  [256,1024]
  short* a1   = (short*)(ws + 25690112);   //   131,072 B  W1@V0    [256,256]
  short* a2   = (short*)(ws + 25821184);   //   524,288 B  Wout@V1  [1024,256]
  short* ub   = (short*)(ws + 26345472);   //   262,144 B  U bf16 (2 layers)

  // a0/a1/a2 from f32 inputs + U -> bf16 (4 extra blocks)
  wgemm<<<40, 256, 0, stream>>>(wemb, wf, vfp, wout, ufp, a0, a1, a2, ub);

  // Xc0 = x(f32) @ a0^T -> scan layout
  gemm_x<<<512, 256, 0, stream>>>(xf, a0, xcT0);

  // layer-0 scan, Xc1 = h0 @ a1^T fused into the step epilogue
  scan_fuse<<<256, 256, 0, stream>>>(ub, a1, xcT0, xcT1, hs);

  // layer-1 scan
  scan_rnn<<<512, 256, 0, stream>>>(ub + 65536, xcT1, hbuf, hs + 256);

  // probs = softmax_T(h1 @ a2^T), fused
  gemm_logsm<<<512, 256, 0, stream>>>(hbuf, a2, (float*)d_out);
}

// Round 7
// 226.223 us; speedup vs baseline: 1.5952x; 1.0387x over previous
//
#include <hip/hip_runtime.h>
#include <stdint.h>
#include <stddef.h>

// ---------- types ----------
typedef short s8v __attribute__((ext_vector_type(8)));   // 8 bf16 (4 VGPRs) MFMA A/B frag
typedef short s4v __attribute__((ext_vector_type(4)));   // 4 bf16
typedef float f4v __attribute__((ext_vector_type(4)));   // MFMA C/D frag

#define DEV static __device__ __forceinline__

// Problem constants: B=32 T=512 VOCAB=1024 D=256 H=256 O=1024 L=2
// Pipeline (5 dispatches):
//   wgemm : a0 = W0@Wemb, a1 = W1@V0, a2 = Wout@V1 (f32 inputs) + U->bf16 (4 blocks)
//   gemm_x: Xc0 = x(f32) @ a0^T -> xc FRAG layout (coalesced for the scans)
//   scan_fuse: layer-0 recurrence + Xc1 = h0 @ a1^T fused (xc frag layout in+out)
//   scan_rnn : layer-1 recurrence (xc frag in, hbuf row layout out for logsm)
//   gemm_logsm: softmax_T(h1 @ a2^T), LDS-transposed coalesced out-write
//
// xc FRAG layout: value (g, t, b=g*16+s, k) at
//   XC[(g*512 + t)*4096 + (k>>2)*64 + s*4 + (k&3)]
// A wave's s4v read/write (fixed w,mt; lanes quad,sid) covers (16w+4mt+quad)*64
// + sid*4 -> 512 B contiguous per instruction (vs 8-B gathers in row layout).

DEV short f2b(float f) {
  union { float f; uint32_t u; } v; v.f = f;
  uint32_t u = v.u;
  uint32_t r = (u + 0x7fffu + ((u >> 16) & 1u)) >> 16;   // RNE
  return (short)(uint16_t)r;
}
DEV float b2f(short h) {
  union { uint32_t u; float f; } v; v.u = ((uint32_t)(uint16_t)h) << 16;
  return v.f;
}

DEV void gl_lds16(const void* g, void* l) {
  __builtin_amdgcn_global_load_lds(
      (__attribute__((address_space(1))) void*)(uintptr_t)(g),
      (__attribute__((address_space(3))) void*)(l), 16, 0, 0);
}

// conflict-free hT layout: hT[s][k] stored at [kb][q][s][j], k = kb*32 + q*8 + j.
DEV int hoff(int s, int k) {
  return ((k >> 5) << 9) + (((k >> 3) & 3) << 7) + (s << 3) + (k & 7);
}

// ---------- weight-product GEMMs straight from f32 + U bf16 convert ----------
DEV void wgemm_body(const float* __restrict__ Af, const float* __restrict__ Bsrc,
                    short* __restrict__ C, int lda, int ldbs, int ldc,
                    int m0, int n0, int tid, short* As, float* Bf) {
  const int w = tid >> 6, lane = tid & 63, quad = lane >> 4, sid = lane & 15;
  const int wm = (w >> 1) * 64, wn = (w & 1) * 64;

  f4v acc[4][4];
#pragma unroll
  for (int i = 0; i < 4; ++i)
#pragma unroll
    for (int j = 0; j < 4; ++j) acc[i][j] = (f4v){0.f, 0.f, 0.f, 0.f};

  for (int k0 = 0; k0 < 256; k0 += 64) {
#pragma unroll
    for (int q = 0; q < 8; ++q) {
      int lin = q * 256 + tid;
      int kr = lin >> 5, nc = (lin & 31) << 2;
      gl_lds16(Bsrc + (size_t)(k0 + kr) * ldbs + n0 + nc, &Bf[lin << 2]);
    }
#pragma unroll
    for (int q = 0; q < 4; ++q) {
      int lin = q * 256 + tid;
      int row = lin >> 3, kc = (lin & 7) << 3;
      const float* ap = Af + (size_t)(m0 + row) * lda + k0 + kc;
      float4 v0 = *(const float4*)ap;
      float4 v1 = *(const float4*)(ap + 4);
      s8v p;
      p[0] = f2b(v0.x); p[1] = f2b(v0.y); p[2] = f2b(v0.z); p[3] = f2b(v0.w);
      p[4] = f2b(v1.x); p[5] = f2b(v1.y); p[6] = f2b(v1.z); p[7] = f2b(v1.w);
      *(s8v*)&As[row * 72 + kc] = p;
    }
    __syncthreads();
#pragma unroll
    for (int kb = 0; kb < 2; ++kb) {
      s8v af[4], bf[4];
#pragma unroll
      for (int mt = 0; mt < 4; ++mt)
        af[mt] = *(const s8v*)&As[(wm + 16 * mt + sid) * 72 + kb * 32 + quad * 8];
#pragma unroll
      for (int nt = 0; nt < 4; ++nt) {
        s8v b;
#pragma unroll
        for (int j = 0; j < 8; ++j)
          b[j] = f2b(Bf[(kb * 32 + quad * 8 + j) * 128 + wn + 16 * nt + sid]);
        bf[nt] = b;
      }
#pragma unroll
      for (int mt = 0; mt < 4; ++mt)
#pragma unroll
        for (int nt = 0; nt < 4; ++nt)
          acc[mt][nt] = __builtin_amdgcn_mfma_f32_16x16x32_bf16(af[mt], bf[nt], acc[mt][nt], 0, 0, 0);
    }
    __syncthreads();
  }
#pragma unroll
  for (int mt = 0; mt < 4; ++mt)
#pragma unroll
    for (int r = 0; r < 4; ++r) {
      int gm = m0 + wm + 16 * mt + 4 * quad + r;
      size_t ro = (size_t)gm * ldc;
#pragma unroll
      for (int nt = 0; nt < 4; ++nt)
        C[ro + n0 + wn + 16 * nt + sid] = f2b(acc[mt][nt][r]);
    }
}

__global__ __launch_bounds__(256) void wgemm(const float* __restrict__ wemb,
                                             const float* __restrict__ wf,
                                             const float* __restrict__ vfp,
                                             const float* __restrict__ wout,
                                             const float* __restrict__ ufp,
                                             short* __restrict__ a0,
                                             short* __restrict__ a1,
                                             short* __restrict__ a2,
                                             short* __restrict__ ub) {
  __shared__ __align__(16) short As[128 * 72];   // 18 KB
  __shared__ __align__(16) float Bf[64 * 128];   // 32 KB
  const int blk = blockIdx.x, tid = threadIdx.x;
  if (blk < 16) {          // a0 = W0 @ Wemb : [256,1024], 2x8 tiles
    wgemm_body(wf, wemb, a0, 256, 1024, 1024,
               (blk >> 3) * 128, (blk & 7) * 128, tid, As, Bf);
  } else if (blk < 20) {   // a1 = W1 @ V0 : [256,256], 2x2 tiles
    int b = blk - 16;
    wgemm_body(wf + 65536, vfp, a1, 256, 256, 256,
               (b >> 1) * 128, (b & 1) * 128, tid, As, Bf);
  } else if (blk < 36) {   // a2 = Wout @ V1 : [1024,256], 8x2 tiles
    int b = blk - 20;
    wgemm_body(wout, vfp + 65536, a2, 256, 256, 256,
               (b >> 1) * 128, (b & 1) * 128, tid, As, Bf);
  } else {                 // blk 36..39: U (2 layers, 512 KB f32) -> bf16 once
    int b = blk - 36;
    const float* src = ufp + (size_t)b * 32768;
    short* dst = ub + (size_t)b * 32768;
#pragma unroll 4
    for (int i = tid; i < 8192; i += 256) {
      float4 v = ((const float4*)src)[i];
      s4v q; q.x = f2b(v.x); q.y = f2b(v.y); q.z = f2b(v.z); q.w = f2b(v.w);
      ((s4v*)dst)[i] = q;
    }
  }
}

// ---------- Xc0 = x(f32) @ A0^T -> xc frag layout ----------
// Block = (g, t-pair): 32 rows = 16 b's x 2 t's (A staging is row-granular so the
// scattered m-mapping is free). C emitted via LDS transpose (Bs reuse) as two
// contiguous 8-KB frag-layout runs.
__global__ __launch_bounds__(256, 2) void gemm_x(const float* __restrict__ Xf,
                                                 const short* __restrict__ Bw,
                                                 short* __restrict__ C) {
  __shared__ __align__(16) short As[32 * 72];    // 4.5 KB
  __shared__ __align__(16) short Bs[256 * 64];   // 32 KB (reused as Ls in epilogue)
  const int tid = threadIdx.x;
  const int w = tid >> 6, lane = tid & 63, quad = lane >> 4, sid = lane & 15;
  const int g = blockIdx.x >> 8, tp = blockIdx.x & 255;
  const int wn = w * 64;

  f4v acc[2][4];
#pragma unroll
  for (int i = 0; i < 2; ++i)
#pragma unroll
    for (int j = 0; j < 4; ++j) acc[i][j] = (f4v){0.f, 0.f, 0.f, 0.f};

  for (int k0 = 0; k0 < 1024; k0 += 64) {
#pragma unroll
    for (int q = 0; q < 8; ++q) {
      int lin = q * 256 + tid;
      gl_lds16(Bw + (size_t)(lin >> 3) * 1024 + k0 + ((lin & 7) << 3), &Bs[lin << 3]);
    }
    {
      int row = tid >> 3, kc = (tid & 7) << 3;
      // lr -> m: m = (g*16 + (lr&15))*512 + 2*tp + (lr>>4)
      int m = (g * 16 + (row & 15)) * 512 + 2 * tp + (row >> 4);
      const float* ap = &Xf[(size_t)m * 1024 + k0 + kc];
      float4 v0 = *(const float4*)ap;
      float4 v1 = *(const float4*)(ap + 4);
      s8v p;
      p[0] = f2b(v0.x); p[1] = f2b(v0.y); p[2] = f2b(v0.z); p[3] = f2b(v0.w);
      p[4] = f2b(v1.x); p[5] = f2b(v1.y); p[6] = f2b(v1.z); p[7] = f2b(v1.w);
      *(s8v*)&As[row * 72 + kc] = p;
    }
    __syncthreads();
#pragma unroll
    for (int kb = 0; kb < 2; ++kb) {
      s8v af[2], bf[4];
#pragma unroll
      for (int mt = 0; mt < 2; ++mt)
        af[mt] = *(const s8v*)&As[(16 * mt + sid) * 72 + kb * 32 + quad * 8];
#pragma unroll
      for (int nt = 0; nt < 4; ++nt)
        bf[nt] = *(const s8v*)&Bs[(wn + 16 * nt + sid) * 64 + kb * 32 + quad * 8];
#pragma unroll
      for (int mt = 0; mt < 2; ++mt)
#pragma unroll
        for (int nt = 0; nt < 4; ++nt)
          acc[mt][nt] = __builtin_amdgcn_mfma_f32_16x16x32_bf16(af[mt], bf[nt], acc[mt][nt], 0, 0, 0);
    }
    __syncthreads();
  }

  // epilogue: stage C[lr][n] into Ls (pitch 264), then frag-layout contiguous write
  short* Ls = Bs;
#pragma unroll
  for (int mt = 0; mt < 2; ++mt)
#pragma unroll
    for (int nt = 0; nt < 4; ++nt) {
      int n = wn + 16 * nt + sid;
#pragma unroll
      for (int r = 0; r < 4; ++r)
        Ls[(16 * mt + 4 * quad + r) * 264 + n] = f2b(acc[mt][nt][r]);
    }
  __syncthreads();
  {
    const size_t obase = (size_t)((g << 9) + 2 * tp) * 4096;
#pragma unroll
    for (int h = 0; h < 2; ++h) {
      int q = h * 256 + tid;            // 0..511
      int tl = q >> 8, q16 = q & 255;
      int ch = q16 >> 3, qq = q16 & 7;
      s4v lo = *(const s4v*)&Ls[(tl * 16 + 2 * qq) * 264 + ch * 4];
      s4v hi = *(const s4v*)&Ls[(tl * 16 + 2 * qq + 1) * 264 + ch * 4];
      s8v v;
      v[0] = lo.x; v[1] = lo.y; v[2] = lo.z; v[3] = lo.w;
      v[4] = hi.x; v[5] = hi.y; v[6] = hi.z; v[7] = hi.w;
      *(s8v*)&C[obase + (size_t)tl * 4096 + q16 * 8] = v;
    }
  }
}

// ---------- layer-0 scan fused with Xc1 = h0 @ A1^T ----------
// xc in/out in frag layout: every xc access is 512-B contiguous per wave instr.
__global__ __launch_bounds__(256, 1) void scan_fuse(const short* __restrict__ Ub,
                                                    const short* __restrict__ A1b,
                                                    const short* __restrict__ XcIn,
                                                    short* __restrict__ XcOut,
                                                    const float* __restrict__ hinit) {
  constexpr int CL = 4, WU = 12, NC = 128;
  __shared__ __align__(16) short hT[2][4096];
  const int tid = threadIdx.x;
  const int w = tid >> 6, lane = tid & 63, quad = lane >> 4, sid = lane & 15;
  const int c = blockIdx.x & (NC - 1);
  const int g = blockIdx.x >> 7;
  const int laneoff = quad * 64 + sid * 4;

  s8v uf[4][8], vf[4][8];
#pragma unroll
  for (int mt = 0; mt < 4; ++mt)
#pragma unroll
    for (int kb = 0; kb < 8; ++kb) {
      int i = 64 * w + 16 * mt + sid;
      int k = 32 * kb + quad * 8;
      uf[mt][kb] = *(const s8v*)&Ub[i * 256 + k];
      vf[mt][kb] = *(const s8v*)&A1b[i * 256 + k];
    }

  const int t0 = (c * CL <= WU) ? 0 : c * CL - WU;
  const int t1 = (c + 1) * CL;

  for (int idx = tid; idx < 4096; idx += 256) {
    int s = idx >> 8, i = idx & 255;
    hT[0][hoff(s, i)] = (t0 == 0) ? f2b(hinit[i]) : (short)0;
  }
  __syncthreads();

  // prefetch xc for t0 (frag layout)
  s4v xcn[4];
  {
    const size_t xb = (size_t)((g << 9) + t0) * 4096 + 1024 * w + laneoff;
#pragma unroll
    for (int mt = 0; mt < 4; ++mt)
      xcn[mt] = *(const s4v*)&XcIn[xb + 256 * mt];
  }

  int pr = 0;
  for (int t = t0; t <= t1; ++t) {
    s8v bf[8];
#pragma unroll
    for (int kb = 0; kb < 8; ++kb)
      bf[kb] = *(const s8v*)&hT[pr][kb * 512 + quad * 128 + sid * 8];
    const bool doh = (t < t1);
    s4v xcc[4];
    if (doh) {
#pragma unroll
      for (int mt = 0; mt < 4; ++mt) xcc[mt] = xcn[mt];
    }
    if (t + 1 < t1) {   // issue next step's xc loads (hidden under MFMA passes)
      const size_t xb = (size_t)((g << 9) + t + 1) * 4096 + 1024 * w + laneoff;
#pragma unroll
      for (int mt = 0; mt < 4; ++mt)
        xcn[mt] = *(const s4v*)&XcIn[xb + 256 * mt];
    }

    if (t > c * CL) {  // emit xc1_{t-1} = h_{t-1} @ A1^T (owned, warmed rows only)
      f4v ax[4];
#pragma unroll
      for (int mt = 0; mt < 4; ++mt) ax[mt] = (f4v){0.f, 0.f, 0.f, 0.f};
#pragma unroll
      for (int kb = 0; kb < 8; ++kb)
#pragma unroll
        for (int mt = 0; mt < 4; ++mt)
          ax[mt] = __builtin_amdgcn_mfma_f32_16x16x32_bf16(vf[mt][kb], bf[kb], ax[mt], 0, 0, 0);
      const size_t ob = (size_t)((g << 9) + (t - 1)) * 4096 + 1024 * w + laneoff;
#pragma unroll
      for (int mt = 0; mt < 4; ++mt) {
        s4v p; p.x = f2b(ax[mt].x); p.y = f2b(ax[mt].y);
        p.z = f2b(ax[mt].z); p.w = f2b(ax[mt].w);
        *(s4v*)&XcOut[ob + 256 * mt] = p;
      }
    }

    if (doh) {
      f4v acc[4];
#pragma unroll
      for (int mt = 0; mt < 4; ++mt) acc[mt] = (f4v){0.f, 0.f, 0.f, 0.f};
#pragma unroll
      for (int kb = 0; kb < 8; ++kb)
#pragma unroll
        for (int mt = 0; mt < 4; ++mt)
          acc[mt] = __builtin_amdgcn_mfma_f32_16x16x32_bf16(uf[mt][kb], bf[kb], acc[mt], 0, 0, 0);
#pragma unroll
      for (int mt = 0; mt < 4; ++mt) {
        int k0 = 64 * w + 16 * mt + 4 * quad;
        f4v v = acc[mt];
        v.x += b2f(xcc[mt].x); v.y += b2f(xcc[mt].y);
        v.z += b2f(xcc[mt].z); v.w += b2f(xcc[mt].w);
        s4v p; p.x = f2b(v.x); p.y = f2b(v.y); p.z = f2b(v.z); p.w = f2b(v.w);
        *(s4v*)&hT[pr ^ 1][hoff(sid, k0)] = p;
      }
    }
    pr ^= 1;
    __syncthreads();
  }
}

// ---------- chunked recurrence scan (layer 1) ----------
// xc in frag layout; hbuf out stays row layout (consumed row-wise by logsm).
__global__ __launch_bounds__(256, 2) void scan_rnn(const short* __restrict__ Ub,
                                                   const short* __restrict__ XcT,
                                                   short* __restrict__ hbuf,
                                                   const float* __restrict__ hinit) {
  constexpr int CL = 2, WU = 12, NC = 256;
  __shared__ __align__(16) short hT[2][4096];
  const int tid = threadIdx.x;
  const int w = tid >> 6, lane = tid & 63, quad = lane >> 4, sid = lane & 15;
  const int c = blockIdx.x & (NC - 1);
  const int g = blockIdx.x >> 8;
  const int laneoff = quad * 64 + sid * 4;

  s8v uf[4][8];
#pragma unroll
  for (int mt = 0; mt < 4; ++mt)
#pragma unroll
    for (int kb = 0; kb < 8; ++kb) {
      int i = 64 * w + 16 * mt + sid;
      int k = 32 * kb + quad * 8;
      uf[mt][kb] = *(const s8v*)&Ub[i * 256 + k];
    }

  const int t0 = (c * CL <= WU) ? 0 : c * CL - WU;
  const int t1 = (c + 1) * CL;

  for (int idx = tid; idx < 4096; idx += 256) {
    int s = idx >> 8, i = idx & 255;
    hT[0][hoff(s, i)] = (t0 == 0) ? f2b(hinit[i]) : (short)0;
  }
  __syncthreads();

  s4v xcn[4];
  {
    const size_t xb = (size_t)((g << 9) + t0) * 4096 + 1024 * w + laneoff;
#pragma unroll
    for (int mt = 0; mt < 4; ++mt)
      xcn[mt] = *(const s4v*)&XcT[xb + 256 * mt];
  }

  int pr = 0;
  for (int t = t0; t < t1; ++t) {
    s8v bf[8];
#pragma unroll
    for (int kb = 0; kb < 8; ++kb)
      bf[kb] = *(const s8v*)&hT[pr][kb * 512 + quad * 128 + sid * 8];
    s4v xcc[4];
#pragma unroll
    for (int mt = 0; mt < 4; ++mt) xcc[mt] = xcn[mt];
    if (t + 1 < t1) {
      const size_t xb = (size_t)((g << 9) + t + 1) * 4096 + 1024 * w + laneoff;
#pragma unroll
      for (int mt = 0; mt < 4; ++mt)
        xcn[mt] = *(const s4v*)&XcT[xb + 256 * mt];
    }

    f4v acc[4];
#pragma unroll
    for (int mt = 0; mt < 4; ++mt) acc[mt] = (f4v){0.f, 0.f, 0.f, 0.f};
#pragma unroll
    for (int kb = 0; kb < 8; ++kb)
#pragma unroll
      for (int mt = 0; mt < 4; ++mt)
        acc[mt] = __builtin_amdgcn_mfma_f32_16x16x32_bf16(uf[mt][kb], bf[kb], acc[mt], 0, 0, 0);

    const bool emit = (t >= c * CL);
    const size_t xbase = ((size_t)((g << 9) + t) * 16 + sid) * 256;
#pragma unroll
    for (int mt = 0; mt < 4; ++mt) {
      int k0 = 64 * w + 16 * mt + 4 * quad;
      f4v v = acc[mt];
      v.x += b2f(xcc[mt].x); v.y += b2f(xcc[mt].y);
      v.z += b2f(xcc[mt].z); v.w += b2f(xcc[mt].w);
      s4v p; p.x = f2b(v.x); p.y = f2b(v.y); p.z = f2b(v.z); p.w = f2b(v.w);
      *(s4v*)&hT[pr ^ 1][hoff(sid, k0)] = p;
      if (emit) *(s4v*)&hbuf[xbase + k0] = p;
    }
    pr ^= 1;
    __syncthreads();
  }
}

// ---------- fused logits GEMM + softmax over T ----------
// GEMM unchanged; epilogue now stages probabilities into LDS (As reuse) and
// writes out in 256-B contiguous float4 runs (was 128 scattered dwords/lane).
__global__ __launch_bounds__(256, 2) void gemm_logsm(const short* __restrict__ A,
                                                     const short* __restrict__ Bw,
                                                     float* __restrict__ out) {
  __shared__ __align__(16) short As[512 * 40];   // 40960 B; reused as Ps (f32) in epilogue
  __shared__ __align__(16) short Bs[64 * 32];
  __shared__ float2 red[4][64];
  const int tid = threadIdx.x;
  const int w = tid >> 6, lane = tid & 63, quad = lane >> 4, sid = lane & 15;
  const int b = blockIdx.x & 31, ot = blockIdx.x >> 5;
  const int g = b >> 4, si = b & 15;

  f4v acc[8][4];
#pragma unroll
  for (int i = 0; i < 8; ++i)
#pragma unroll
    for (int j = 0; j < 4; ++j) acc[i][j] = (f4v){0.f, 0.f, 0.f, 0.f};

  for (int k0 = 0; k0 < 256; k0 += 32) {
#pragma unroll
    for (int q = 0; q < 8; ++q) {
      int lin = q * 256 + tid;
      int t = lin >> 2, kch = lin & 3;
      size_t ar = ((size_t)(g * 512 + t) * 16 + si) * 256;
      s8v v = *(const s8v*)(A + ar + k0 + kch * 8);
      *(s8v*)&As[t * 40 + kch * 8] = v;
    }
    {
      int row = tid & 63, kch = tid >> 6;
      s8v v = *(const s8v*)(Bw + (size_t)(ot * 64 + row) * 256 + k0 + kch * 8);
      *(s8v*)&Bs[tid << 3] = v;
    }
    __syncthreads();
    s8v bf[4];
#pragma unroll
    for (int nt = 0; nt < 4; ++nt)
      bf[nt] = *(const s8v*)&Bs[(quad * 64 + 16 * nt + sid) * 8];
#pragma unroll
    for (int mt = 0; mt < 8; ++mt) {
      s8v af = *(const s8v*)&As[(128 * w + 16 * mt + sid) * 40 + quad * 8];
#pragma unroll
      for (int nt = 0; nt < 4; ++nt)
        acc[mt][nt] = __builtin_amdgcn_mfma_f32_16x16x32_bf16(af, bf[nt], acc[mt][nt], 0, 0, 0);
    }
    __syncthreads();
  }

  // softmax stats over t per column (16nt+sid)
  float Mv[4], Iv[4];
#pragma unroll
  for (int nt = 0; nt < 4; ++nt) {
    float m = -3.0e38f;
#pragma unroll
    for (int mt = 0; mt < 8; ++mt)
#pragma unroll
      for (int r = 0; r < 4; ++r) m = fmaxf(m, acc[mt][nt][r]);
    float sum = 0.f;
#pragma unroll
    for (int mt = 0; mt < 8; ++mt)
#pragma unroll
      for (int r = 0; r < 4; ++r) sum += __expf(acc[mt][nt][r] - m);
#pragma unroll
    for (int d = 16; d < 64; d <<= 1) {
      float om = __shfl_xor(m, d, 64);
      float os = __shfl_xor(sum, d, 64);
      float nm = fmaxf(m, om);
      sum = sum * __expf(m - nm) + os * __expf(om - nm);
      m = nm;
    }
    if (quad == 0) red[w][16 * nt + sid] = (float2){m, sum};
  }
  __syncthreads();
#pragma unroll
  for (int nt = 0; nt < 4; ++nt) {
    float M = -3.0e38f, S = 0.f;
#pragma unroll
    for (int ww = 0; ww < 4; ++ww) {
      float2 r2 = red[ww][16 * nt + sid];
      float nm = fmaxf(M, r2.x);
      S = S * __expf(M - nm) + r2.y * __expf(r2.x - nm);
      M = nm;
    }
    Mv[nt] = M;
    Iv[nt] = 1.0f / S;
  }
  __syncthreads();

  // coalesced out-write: per wave-pass, stage [128 t][64 o] f32 in LDS, then
  // 256 threads write 16 rows x 256 B contiguous per instruction.
  float* Ps = (float*)As;                        // [128][68] f32 = 34816 B
  const size_t obb = (size_t)b * 524288 + ot * 64;
#pragma unroll
  for (int ww = 0; ww < 4; ++ww) {
    if (w == ww) {
#pragma unroll
      for (int mt = 0; mt < 8; ++mt)
#pragma unroll
        for (int nt = 0; nt < 4; ++nt)
#pragma unroll
          for (int r = 0; r < 4; ++r)
            Ps[(16 * mt + 4 * quad + r) * 68 + 16 * nt + sid] =
                __expf(acc[mt][nt][r] - Mv[nt]) * Iv[nt];
    }
    __syncthreads();
    {
      const int tl = tid >> 4, c4 = tid & 15;
#pragma unroll
      for (int s2 = 0; s2 < 8; ++s2) {
        int row = s2 * 16 + tl;
        float4 v = *(const float4*)&Ps[row * 68 + c4 * 4];
        *(float4*)&out[obb + (size_t)(ww * 128 + row) * 1024 + c4 * 4] = v;
      }
    }
    __syncthreads();
  }
}

// ---------- host ----------
extern "C" void kernel_launch(void* const* d_in, const int* in_sizes, int n_in,
                              void* d_out, int out_size, void* d_ws, size_t ws_size,
                              hipStream_t stream) {
  (void)in_sizes; (void)n_in; (void)out_size; (void)ws_size;
  const float* xf   = (const float*)d_in[0];
  const float* hs   = (const float*)d_in[1];
  const float* wemb = (const float*)d_in[2];
  const float* wf   = (const float*)d_in[3];
  const float* ufp  = (const float*)d_in[4];
  const float* vfp  = (const float*)d_in[5];
  const float* wout = (const float*)d_in[6];

  char* ws = (char*)d_ws;
  short* hbuf = (short*)(ws);              // 8,388,608 B  layer-1 h, row layout
  short* xcT0 = (short*)(ws + 8388608);    // 8,388,608 B  Xc0 frag layout
  short* xcT1 = (short*)(ws + 16777216);   // 8,388,608 B  Xc1 frag layout
  short* a0   = (short*)(ws + 25165824);   //   524,288 B  W0@Wemb  [256,1024]
  short* a1   = (short*)(ws + 25690112);   //   131,072 B  W1@V0    [256,256]
  short* a2   = (short*)(ws + 25821184);   //   524,288 B  Wout@V1  [1024,256]
  short* ub   = (short*)(ws + 26345472);   //   262,144 B  U bf16 (2 layers)

  // a0/a1/a2 from f32 inputs + U -> bf16
  wgemm<<<40, 256, 0, stream>>>(wemb, wf, vfp, wout, ufp, a0, a1, a2, ub);

  // Xc0 = x(f32) @ a0^T -> frag layout
  gemm_x<<<512, 256, 0, stream>>>(xf, a0, xcT0);

  // layer-0 scan, Xc1 = h0 @ a1^T fused (frag in/out)
  scan_fuse<<<256, 256, 0, stream>>>(ub, a1, xcT0, xcT1, hs);

  // layer-1 scan (frag in, row out)
  scan_rnn<<<512, 256, 0, stream>>>(ub + 65536, xcT1, hbuf, hs + 256);

  // probs = softmax_T(h1 @ a2^T), fused, coalesced out
  gemm_logsm<<<512, 256, 0, stream>>>(hbuf, a2, (float*)d_out);
}

// Round 8
// 224.589 us; speedup vs baseline: 1.6068x; 1.0073x over previous
//
#include <hip/hip_runtime.h>
#include <stdint.h>
#include <stddef.h>

// ---------- types ----------
typedef short s8v __attribute__((ext_vector_type(8)));   // 8 bf16 (4 VGPRs) MFMA A/B frag
typedef short s4v __attribute__((ext_vector_type(4)));   // 4 bf16
typedef float f4v __attribute__((ext_vector_type(4)));   // MFMA C/D frag

#define DEV static __device__ __forceinline__

// Problem constants: B=32 T=512 VOCAB=1024 D=256 H=256 O=1024 L=2
// Pipeline (5 dispatches):
//   wgemm : a0 = W0@Wemb, a1 = W1@V0, a2 = Wout@V1 (f32 inputs) + U->bf16 (4 blocks)
//   gemm_x: Xc0 = x(f32) @ a0^T -> xc FRAG layout (coalesced for the scans)
//   scan_fuse: layer-0 recurrence + Xc1 = h0 @ a1^T fused (xc frag layout in+out)
//   scan_rnn : layer-1 recurrence (xc frag in, hbuf row layout out for logsm)
//   gemm_logsm: softmax_T(h1 @ a2^T), parallel LDS-transposed coalesced out-write

DEV short f2b(float f) {
  union { float f; uint32_t u; } v; v.f = f;
  uint32_t u = v.u;
  uint32_t r = (u + 0x7fffu + ((u >> 16) & 1u)) >> 16;   // RNE
  return (short)(uint16_t)r;
}
DEV float b2f(short h) {
  union { uint32_t u; float f; } v; v.u = ((uint32_t)(uint16_t)h) << 16;
  return v.f;
}

DEV void gl_lds16(const void* g, void* l) {
  __builtin_amdgcn_global_load_lds(
      (__attribute__((address_space(1))) void*)(uintptr_t)(g),
      (__attribute__((address_space(3))) void*)(l), 16, 0, 0);
}

// conflict-free hT layout: hT[s][k] stored at [kb][q][s][j], k = kb*32 + q*8 + j.
DEV int hoff(int s, int k) {
  return ((k >> 5) << 9) + (((k >> 3) & 3) << 7) + (s << 3) + (k & 7);
}

// ---------- weight-product GEMMs straight from f32 + U bf16 convert ----------
DEV void wgemm_body(const float* __restrict__ Af, const float* __restrict__ Bsrc,
                    short* __restrict__ C, int lda, int ldbs, int ldc,
                    int m0, int n0, int tid, short* As, float* Bf) {
  const int w = tid >> 6, lane = tid & 63, quad = lane >> 4, sid = lane & 15;
  const int wm = (w >> 1) * 64, wn = (w & 1) * 64;

  f4v acc[4][4];
#pragma unroll
  for (int i = 0; i < 4; ++i)
#pragma unroll
    for (int j = 0; j < 4; ++j) acc[i][j] = (f4v){0.f, 0.f, 0.f, 0.f};

  for (int k0 = 0; k0 < 256; k0 += 64) {
#pragma unroll
    for (int q = 0; q < 8; ++q) {
      int lin = q * 256 + tid;
      int kr = lin >> 5, nc = (lin & 31) << 2;
      gl_lds16(Bsrc + (size_t)(k0 + kr) * ldbs + n0 + nc, &Bf[lin << 2]);
    }
#pragma unroll
    for (int q = 0; q < 4; ++q) {
      int lin = q * 256 + tid;
      int row = lin >> 3, kc = (lin & 7) << 3;
      const float* ap = Af + (size_t)(m0 + row) * lda + k0 + kc;
      float4 v0 = *(const float4*)ap;
      float4 v1 = *(const float4*)(ap + 4);
      s8v p;
      p[0] = f2b(v0.x); p[1] = f2b(v0.y); p[2] = f2b(v0.z); p[3] = f2b(v0.w);
      p[4] = f2b(v1.x); p[5] = f2b(v1.y); p[6] = f2b(v1.z); p[7] = f2b(v1.w);
      *(s8v*)&As[row * 72 + kc] = p;
    }
    __syncthreads();
#pragma unroll
    for (int kb = 0; kb < 2; ++kb) {
      s8v af[4], bf[4];
#pragma unroll
      for (int mt = 0; mt < 4; ++mt)
        af[mt] = *(const s8v*)&As[(wm + 16 * mt + sid) * 72 + kb * 32 + quad * 8];
#pragma unroll
      for (int nt = 0; nt < 4; ++nt) {
        s8v b;
#pragma unroll
        for (int j = 0; j < 8; ++j)
          b[j] = f2b(Bf[(kb * 32 + quad * 8 + j) * 128 + wn + 16 * nt + sid]);
        bf[nt] = b;
      }
#pragma unroll
      for (int mt = 0; mt < 4; ++mt)
#pragma unroll
        for (int nt = 0; nt < 4; ++nt)
          acc[mt][nt] = __builtin_amdgcn_mfma_f32_16x16x32_bf16(af[mt], bf[nt], acc[mt][nt], 0, 0, 0);
    }
    __syncthreads();
  }
#pragma unroll
  for (int mt = 0; mt < 4; ++mt)
#pragma unroll
    for (int r = 0; r < 4; ++r) {
      int gm = m0 + wm + 16 * mt + 4 * quad + r;
      size_t ro = (size_t)gm * ldc;
#pragma unroll
      for (int nt = 0; nt < 4; ++nt)
        C[ro + n0 + wn + 16 * nt + sid] = f2b(acc[mt][nt][r]);
    }
}

__global__ __launch_bounds__(256) void wgemm(const float* __restrict__ wemb,
                                             const float* __restrict__ wf,
                                             const float* __restrict__ vfp,
                                             const float* __restrict__ wout,
                                             const float* __restrict__ ufp,
                                             short* __restrict__ a0,
                                             short* __restrict__ a1,
                                             short* __restrict__ a2,
                                             short* __restrict__ ub) {
  __shared__ __align__(16) short As[128 * 72];   // 18 KB
  __shared__ __align__(16) float Bf[64 * 128];   // 32 KB
  const int blk = blockIdx.x, tid = threadIdx.x;
  if (blk < 16) {          // a0 = W0 @ Wemb : [256,1024], 2x8 tiles
    wgemm_body(wf, wemb, a0, 256, 1024, 1024,
               (blk >> 3) * 128, (blk & 7) * 128, tid, As, Bf);
  } else if (blk < 20) {   // a1 = W1 @ V0 : [256,256], 2x2 tiles
    int b = blk - 16;
    wgemm_body(wf + 65536, vfp, a1, 256, 256, 256,
               (b >> 1) * 128, (b & 1) * 128, tid, As, Bf);
  } else if (blk < 36) {   // a2 = Wout @ V1 : [1024,256], 8x2 tiles
    int b = blk - 20;
    wgemm_body(wout, vfp + 65536, a2, 256, 256, 256,
               (b >> 1) * 128, (b & 1) * 128, tid, As, Bf);
  } else {                 // blk 36..39: U (2 layers, 512 KB f32) -> bf16 once
    int b = blk - 36;
    const float* src = ufp + (size_t)b * 32768;
    short* dst = ub + (size_t)b * 32768;
#pragma unroll 4
    for (int i = tid; i < 8192; i += 256) {
      float4 v = ((const float4*)src)[i];
      s4v q; q.x = f2b(v.x); q.y = f2b(v.y); q.z = f2b(v.z); q.w = f2b(v.w);
      ((s4v*)dst)[i] = q;
    }
  }
}

// ---------- Xc0 = x(f32) @ A0^T -> xc frag layout ----------
__global__ __launch_bounds__(256, 2) void gemm_x(const float* __restrict__ Xf,
                                                 const short* __restrict__ Bw,
                                                 short* __restrict__ C) {
  __shared__ __align__(16) short As[32 * 72];    // 4.5 KB
  __shared__ __align__(16) short Bs[256 * 64];   // 32 KB (reused as Ls in epilogue)
  const int tid = threadIdx.x;
  const int w = tid >> 6, lane = tid & 63, quad = lane >> 4, sid = lane & 15;
  const int g = blockIdx.x >> 8, tp = blockIdx.x & 255;
  const int wn = w * 64;

  f4v acc[2][4];
#pragma unroll
  for (int i = 0; i < 2; ++i)
#pragma unroll
    for (int j = 0; j < 4; ++j) acc[i][j] = (f4v){0.f, 0.f, 0.f, 0.f};

  for (int k0 = 0; k0 < 1024; k0 += 64) {
#pragma unroll
    for (int q = 0; q < 8; ++q) {
      int lin = q * 256 + tid;
      gl_lds16(Bw + (size_t)(lin >> 3) * 1024 + k0 + ((lin & 7) << 3), &Bs[lin << 3]);
    }
    {
      int row = tid >> 3, kc = (tid & 7) << 3;
      int m = (g * 16 + (row & 15)) * 512 + 2 * tp + (row >> 4);
      const float* ap = &Xf[(size_t)m * 1024 + k0 + kc];
      float4 v0 = *(const float4*)ap;
      float4 v1 = *(const float4*)(ap + 4);
      s8v p;
      p[0] = f2b(v0.x); p[1] = f2b(v0.y); p[2] = f2b(v0.z); p[3] = f2b(v0.w);
      p[4] = f2b(v1.x); p[5] = f2b(v1.y); p[6] = f2b(v1.z); p[7] = f2b(v1.w);
      *(s8v*)&As[row * 72 + kc] = p;
    }
    __syncthreads();
#pragma unroll
    for (int kb = 0; kb < 2; ++kb) {
      s8v af[2], bf[4];
#pragma unroll
      for (int mt = 0; mt < 2; ++mt)
        af[mt] = *(const s8v*)&As[(16 * mt + sid) * 72 + kb * 32 + quad * 8];
#pragma unroll
      for (int nt = 0; nt < 4; ++nt)
        bf[nt] = *(const s8v*)&Bs[(wn + 16 * nt + sid) * 64 + kb * 32 + quad * 8];
#pragma unroll
      for (int mt = 0; mt < 2; ++mt)
#pragma unroll
        for (int nt = 0; nt < 4; ++nt)
          acc[mt][nt] = __builtin_amdgcn_mfma_f32_16x16x32_bf16(af[mt], bf[nt], acc[mt][nt], 0, 0, 0);
    }
    __syncthreads();
  }

  // epilogue: stage C[lr][n] into Ls (pitch 264), then frag-layout contiguous write
  short* Ls = Bs;
#pragma unroll
  for (int mt = 0; mt < 2; ++mt)
#pragma unroll
    for (int nt = 0; nt < 4; ++nt) {
      int n = wn + 16 * nt + sid;
#pragma unroll
      for (int r = 0; r < 4; ++r)
        Ls[(16 * mt + 4 * quad + r) * 264 + n] = f2b(acc[mt][nt][r]);
    }
  __syncthreads();
  {
    const size_t obase = (size_t)((g << 9) + 2 * tp) * 4096;
#pragma unroll
    for (int h = 0; h < 2; ++h) {
      int q = h * 256 + tid;            // 0..511
      int tl = q >> 8, q16 = q & 255;
      int ch = q16 >> 3, qq = q16 & 7;
      s4v lo = *(const s4v*)&Ls[(tl * 16 + 2 * qq) * 264 + ch * 4];
      s4v hi = *(const s4v*)&Ls[(tl * 16 + 2 * qq + 1) * 264 + ch * 4];
      s8v v;
      v[0] = lo.x; v[1] = lo.y; v[2] = lo.z; v[3] = lo.w;
      v[4] = hi.x; v[5] = hi.y; v[6] = hi.z; v[7] = hi.w;
      *(s8v*)&C[obase + (size_t)tl * 4096 + q16 * 8] = v;
    }
  }
}

// ---------- layer-0 scan fused with Xc1 = h0 @ A1^T ----------
__global__ __launch_bounds__(256, 1) void scan_fuse(const short* __restrict__ Ub,
                                                    const short* __restrict__ A1b,
                                                    const short* __restrict__ XcIn,
                                                    short* __restrict__ XcOut,
                                                    const float* __restrict__ hinit) {
  constexpr int CL = 4, WU = 12, NC = 128;
  __shared__ __align__(16) short hT[2][4096];
  const int tid = threadIdx.x;
  const int w = tid >> 6, lane = tid & 63, quad = lane >> 4, sid = lane & 15;
  const int c = blockIdx.x & (NC - 1);
  const int g = blockIdx.x >> 7;
  const int laneoff = quad * 64 + sid * 4;

  s8v uf[4][8], vf[4][8];
#pragma unroll
  for (int mt = 0; mt < 4; ++mt)
#pragma unroll
    for (int kb = 0; kb < 8; ++kb) {
      int i = 64 * w + 16 * mt + sid;
      int k = 32 * kb + quad * 8;
      uf[mt][kb] = *(const s8v*)&Ub[i * 256 + k];
      vf[mt][kb] = *(const s8v*)&A1b[i * 256 + k];
    }

  const int t0 = (c * CL <= WU) ? 0 : c * CL - WU;
  const int t1 = (c + 1) * CL;

  for (int idx = tid; idx < 4096; idx += 256) {
    int s = idx >> 8, i = idx & 255;
    hT[0][hoff(s, i)] = (t0 == 0) ? f2b(hinit[i]) : (short)0;
  }
  __syncthreads();

  s4v xcn[4];
  {
    const size_t xb = (size_t)((g << 9) + t0) * 4096 + 1024 * w + laneoff;
#pragma unroll
    for (int mt = 0; mt < 4; ++mt)
      xcn[mt] = *(const s4v*)&XcIn[xb + 256 * mt];
  }

  int pr = 0;
  for (int t = t0; t <= t1; ++t) {
    s8v bf[8];
#pragma unroll
    for (int kb = 0; kb < 8; ++kb)
      bf[kb] = *(const s8v*)&hT[pr][kb * 512 + quad * 128 + sid * 8];
    const bool doh = (t < t1);
    s4v xcc[4];
    if (doh) {
#pragma unroll
      for (int mt = 0; mt < 4; ++mt) xcc[mt] = xcn[mt];
    }
    if (t + 1 < t1) {   // issue next step's xc loads (hidden under MFMA passes)
      const size_t xb = (size_t)((g << 9) + t + 1) * 4096 + 1024 * w + laneoff;
#pragma unroll
      for (int mt = 0; mt < 4; ++mt)
        xcn[mt] = *(const s4v*)&XcIn[xb + 256 * mt];
    }

    if (t > c * CL) {  // emit xc1_{t-1} = h_{t-1} @ A1^T (owned, warmed rows only)
      f4v ax[4];
#pragma unroll
      for (int mt = 0; mt < 4; ++mt) ax[mt] = (f4v){0.f, 0.f, 0.f, 0.f};
#pragma unroll
      for (int kb = 0; kb < 8; ++kb)
#pragma unroll
        for (int mt = 0; mt < 4; ++mt)
          ax[mt] = __builtin_amdgcn_mfma_f32_16x16x32_bf16(vf[mt][kb], bf[kb], ax[mt], 0, 0, 0);
      const size_t ob = (size_t)((g << 9) + (t - 1)) * 4096 + 1024 * w + laneoff;
#pragma unroll
      for (int mt = 0; mt < 4; ++mt) {
        s4v p; p.x = f2b(ax[mt].x); p.y = f2b(ax[mt].y);
        p.z = f2b(ax[mt].z); p.w = f2b(ax[mt].w);
        *(s4v*)&XcOut[ob + 256 * mt] = p;
      }
    }

    if (doh) {
      f4v acc[4];
#pragma unroll
      for (int mt = 0; mt < 4; ++mt) acc[mt] = (f4v){0.f, 0.f, 0.f, 0.f};
#pragma unroll
      for (int kb = 0; kb < 8; ++kb)
#pragma unroll
        for (int mt = 0; mt < 4; ++mt)
          acc[mt] = __builtin_amdgcn_mfma_f32_16x16x32_bf16(uf[mt][kb], bf[kb], acc[mt], 0, 0, 0);
#pragma unroll
      for (int mt = 0; mt < 4; ++mt) {
        int k0 = 64 * w + 16 * mt + 4 * quad;
        f4v v = acc[mt];
        v.x += b2f(xcc[mt].x); v.y += b2f(xcc[mt].y);
        v.z += b2f(xcc[mt].z); v.w += b2f(xcc[mt].w);
        s4v p; p.x = f2b(v.x); p.y = f2b(v.y); p.z = f2b(v.z); p.w = f2b(v.w);
        *(s4v*)&hT[pr ^ 1][hoff(sid, k0)] = p;
      }
    }
    pr ^= 1;
    __syncthreads();
  }
}

// ---------- chunked recurrence scan (layer 1) ----------
__global__ __launch_bounds__(256, 2) void scan_rnn(const short* __restrict__ Ub,
                                                   const short* __restrict__ XcT,
                                                   short* __restrict__ hbuf,
                                                   const float* __restrict__ hinit) {
  constexpr int CL = 2, WU = 12, NC = 256;
  __shared__ __align__(16) short hT[2][4096];
  const int tid = threadIdx.x;
  const int w = tid >> 6, lane = tid & 63, quad = lane >> 4, sid = lane & 15;
  const int c = blockIdx.x & (NC - 1);
  const int g = blockIdx.x >> 8;
  const int laneoff = quad * 64 + sid * 4;

  s8v uf[4][8];
#pragma unroll
  for (int mt = 0; mt < 4; ++mt)
#pragma unroll
    for (int kb = 0; kb < 8; ++kb) {
      int i = 64 * w + 16 * mt + sid;
      int k = 32 * kb + quad * 8;
      uf[mt][kb] = *(const s8v*)&Ub[i * 256 + k];
    }

  const int t0 = (c * CL <= WU) ? 0 : c * CL - WU;
  const int t1 = (c + 1) * CL;

  for (int idx = tid; idx < 4096; idx += 256) {
    int s = idx >> 8, i = idx & 255;
    hT[0][hoff(s, i)] = (t0 == 0) ? f2b(hinit[i]) : (short)0;
  }
  __syncthreads();

  s4v xcn[4];
  {
    const size_t xb = (size_t)((g << 9) + t0) * 4096 + 1024 * w + laneoff;
#pragma unroll
    for (int mt = 0; mt < 4; ++mt)
      xcn[mt] = *(const s4v*)&XcT[xb + 256 * mt];
  }

  int pr = 0;
  for (int t = t0; t < t1; ++t) {
    s8v bf[8];
#pragma unroll
    for (int kb = 0; kb < 8; ++kb)
      bf[kb] = *(const s8v*)&hT[pr][kb * 512 + quad * 128 + sid * 8];
    s4v xcc[4];
#pragma unroll
    for (int mt = 0; mt < 4; ++mt) xcc[mt] = xcn[mt];
    if (t + 1 < t1) {
      const size_t xb = (size_t)((g << 9) + t + 1) * 4096 + 1024 * w + laneoff;
#pragma unroll
      for (int mt = 0; mt < 4; ++mt)
        xcn[mt] = *(const s4v*)&XcT[xb + 256 * mt];
    }

    f4v acc[4];
#pragma unroll
    for (int mt = 0; mt < 4; ++mt) acc[mt] = (f4v){0.f, 0.f, 0.f, 0.f};
#pragma unroll
    for (int kb = 0; kb < 8; ++kb)
#pragma unroll
      for (int mt = 0; mt < 4; ++mt)
        acc[mt] = __builtin_amdgcn_mfma_f32_16x16x32_bf16(uf[mt][kb], bf[kb], acc[mt], 0, 0, 0);

    const bool emit = (t >= c * CL);
    const size_t xbase = ((size_t)((g << 9) + t) * 16 + sid) * 256;
#pragma unroll
    for (int mt = 0; mt < 4; ++mt) {
      int k0 = 64 * w + 16 * mt + 4 * quad;
      f4v v = acc[mt];
      v.x += b2f(xcc[mt].x); v.y += b2f(xcc[mt].y);
      v.z += b2f(xcc[mt].z); v.w += b2f(xcc[mt].w);
      s4v p; p.x = f2b(v.x); p.y = f2b(v.y); p.z = f2b(v.z); p.w = f2b(v.w);
      *(s4v*)&hT[pr ^ 1][hoff(sid, k0)] = p;
      if (emit) *(s4v*)&hbuf[xbase + k0] = p;
    }
    pr ^= 1;
    __syncthreads();
  }
}

// ---------- fused logits GEMM + softmax over T ----------
// Parallel epilogue: per mt-pass (8 total), ALL 4 waves concurrently stage their
// exp'd 16x64 tile into a private stripe of Ps[64][67] (reuses As), then 256
// threads write 64 rows x 256 B contiguous float4 runs. Pitch 67: staged-write
// ~2-way banks, b128 reads 2-way (3*row+4*c4 distinct mod 4 across rows).
__global__ __launch_bounds__(256, 2) void gemm_logsm(const short* __restrict__ A,
                                                     const short* __restrict__ Bw,
                                                     float* __restrict__ out) {
  __shared__ __align__(16) short As[512 * 40];   // 40960 B; reused as Ps in epilogue
  __shared__ __align__(16) short Bs[64 * 32];
  __shared__ float2 red[4][64];
  const int tid = threadIdx.x;
  const int w = tid >> 6, lane = tid & 63, quad = lane >> 4, sid = lane & 15;
  const int b = blockIdx.x & 31, ot = blockIdx.x >> 5;
  const int g = b >> 4, si = b & 15;

  f4v acc[8][4];
#pragma unroll
  for (int i = 0; i < 8; ++i)
#pragma unroll
    for (int j = 0; j < 4; ++j) acc[i][j] = (f4v){0.f, 0.f, 0.f, 0.f};

  for (int k0 = 0; k0 < 256; k0 += 32) {
#pragma unroll
    for (int q = 0; q < 8; ++q) {
      int lin = q * 256 + tid;
      int t = lin >> 2, kch = lin & 3;
      size_t ar = ((size_t)(g * 512 + t) * 16 + si) * 256;
      s8v v = *(const s8v*)(A + ar + k0 + kch * 8);
      *(s8v*)&As[t * 40 + kch * 8] = v;
    }
    {
      int row = tid & 63, kch = tid >> 6;
      s8v v = *(const s8v*)(Bw + (size_t)(ot * 64 + row) * 256 + k0 + kch * 8);
      *(s8v*)&Bs[tid << 3] = v;
    }
    __syncthreads();
    s8v bf[4];
#pragma unroll
    for (int nt = 0; nt < 4; ++nt)
      bf[nt] = *(const s8v*)&Bs[(quad * 64 + 16 * nt + sid) * 8];
#pragma unroll
    for (int mt = 0; mt < 8; ++mt) {
      s8v af = *(const s8v*)&As[(128 * w + 16 * mt + sid) * 40 + quad * 8];
#pragma unroll
      for (int nt = 0; nt < 4; ++nt)
        acc[mt][nt] = __builtin_amdgcn_mfma_f32_16x16x32_bf16(af, bf[nt], acc[mt][nt], 0, 0, 0);
    }
    __syncthreads();
  }

  // softmax stats over t per column (16nt+sid)
  float Mv[4], Iv[4];
#pragma unroll
  for (int nt = 0; nt < 4; ++nt) {
    float m = -3.0e38f;
#pragma unroll
    for (int mt = 0; mt < 8; ++mt)
#pragma unroll
      for (int r = 0; r < 4; ++r) m = fmaxf(m, acc[mt][nt][r]);
    float sum = 0.f;
#pragma unroll
    for (int mt = 0; mt < 8; ++mt)
#pragma unroll
      for (int r = 0; r < 4; ++r) sum += __expf(acc[mt][nt][r] - m);
#pragma unroll
    for (int d = 16; d < 64; d <<= 1) {
      float om = __shfl_xor(m, d, 64);
      float os = __shfl_xor(sum, d, 64);
      float nm = fmaxf(m, om);
      sum = sum * __expf(m - nm) + os * __expf(om - nm);
      m = nm;
    }
    if (quad == 0) red[w][16 * nt + sid] = (float2){m, sum};
  }
  __syncthreads();
#pragma unroll
  for (int nt = 0; nt < 4; ++nt) {
    float M = -3.0e38f, S = 0.f;
#pragma unroll
    for (int ww = 0; ww < 4; ++ww) {
      float2 r2 = red[ww][16 * nt + sid];
      float nm = fmaxf(M, r2.x);
      S = S * __expf(M - nm) + r2.y * __expf(r2.x - nm);
      M = nm;
    }
    Mv[nt] = M;
    Iv[nt] = 1.0f / S;
  }
  __syncthreads();

  // parallel coalesced out-write: 8 mt-passes; all waves stage concurrently.
  float* Ps = (float*)As;                        // [64][67] f32 = 17152 B
  const size_t obb = (size_t)b * 524288 + ot * 64;
#pragma unroll
  for (int mt = 0; mt < 8; ++mt) {
#pragma unroll
    for (int nt = 0; nt < 4; ++nt)
#pragma unroll
      for (int r = 0; r < 4; ++r)
        Ps[(w * 16 + 4 * quad + r) * 67 + 16 * nt + sid] =
            __expf(acc[mt][nt][r] - Mv[nt]) * Iv[nt];
    __syncthreads();
    {
      const int lr16 = tid >> 4, c4 = tid & 15;
#pragma unroll
      for (int rr = 0; rr < 4; ++rr) {
        int row = rr * 16 + lr16;      // 0..63: wave = row>>4, local t = row&15
        int t = 128 * (row >> 4) + 16 * mt + (row & 15);
        float4 v = *(const float4*)&Ps[row * 67 + c4 * 4];
        *(float4*)&out[obb + (size_t)t * 1024 + c4 * 4] = v;
      }
    }
    __syncthreads();
  }
}

// ---------- host ----------
extern "C" void kernel_launch(void* const* d_in, const int* in_sizes, int n_in,
                              void* d_out, int out_size, void* d_ws, size_t ws_size,
                              hipStream_t stream) {
  (void)in_sizes; (void)n_in; (void)out_size; (void)ws_size;
  const float* xf   = (const float*)d_in[0];
  const float* hs   = (const float*)d_in[1];
  const float* wemb = (const float*)d_in[2];
  const float* wf   = (const float*)d_in[3];
  const float* ufp  = (const float*)d_in[4];
  const float* vfp  = (const float*)d_in[5];
  const float* wout = (const float*)d_in[6];

  char* ws = (char*)d_ws;
  short* hbuf = (short*)(ws);              // 8,388,608 B  layer-1 h, row layout
  short* xcT0 = (short*)(ws + 8388608);    // 8,388,608 B  Xc0 frag layout
  short* xcT1 = (short*)(ws + 16777216);   // 8,388,608 B  Xc1 frag layout
  short* a0   = (short*)(ws + 25165824);   //   524,288 B  W0@Wemb  [256,1024]
  short* a1   = (short*)(ws + 25690112);   //   131,072 B  W1@V0    [256,256]
  short* a2   = (short*)(ws + 25821184);   //   524,288 B  Wout@V1  [1024,256]
  short* ub   = (short*)(ws + 26345472);   //   262,144 B  U bf16 (2 layers)

  // a0/a1/a2 from f32 inputs + U -> bf16
  wgemm<<<40, 256, 0, stream>>>(wemb, wf, vfp, wout, ufp, a0, a1, a2, ub);

  // Xc0 = x(f32) @ a0^T -> frag layout
  gemm_x<<<512, 256, 0, stream>>>(xf, a0, xcT0);

  // layer-0 scan, Xc1 = h0 @ a1^T fused (frag in/out)
  scan_fuse<<<256, 256, 0, stream>>>(ub, a1, xcT0, xcT1, hs);

  // layer-1 scan (frag in, row out)
  scan_rnn<<<512, 256, 0, stream>>>(ub + 65536, xcT1, hbuf, hs + 256);

  // probs = softmax_T(h1 @ a2^T), fused, parallel coalesced out
  gemm_logsm<<<512, 256, 0, stream>>>(hbuf, a2, (float*)d_out);
}